// Round 1
// baseline (5760.984 us; speedup 1.0000x reference)
//
#include <hip/hip_runtime.h>
#include <cstdint>
#include <cstddef>

#define D_MODEL   768
#define D_STATE   64
#define D_INNER   1536
#define HEADDIM   64
#define NHEADS    24
#define D_CONV    4
#define CONV_DIM  1664      // D_INNER + 2*D_STATE
#define D_IN_PROJ 3224      // 2*D_INNER + 2*D_STATE + NHEADS
#define BATCH     4
#define SEQLEN    2048
#define NROWS     (BATCH*SEQLEN)   // 8192

__device__ __forceinline__ int flip_row(int m, const int* __restrict__ lengths) {
    int b = m >> 11;                 // SEQLEN = 2048
    int t = m & (SEQLEN - 1);
    int len = lengths[b];
    int ft = (t < len) ? (len - 1 - t) : t;
    return (b << 11) | ft;
}

// C[m, ccol+n] (+bias[n] +resid[m]) = sum_k A[m,k] * W[n,k]
// A: [8192, K] row-major (rows optionally flip-indexed on read)
// W: [N, K] row-major
// 128x128 tile, BK=16, 256 threads, 8x8 microtile per thread.
__global__ __launch_bounds__(256, 2)
void sgemm_nt(const float* __restrict__ A, const float* __restrict__ W,
              float* __restrict__ C, int N, int K, int ldc, int ccol,
              const int* __restrict__ lengths, int flipA, int flipC,
              const float* __restrict__ bias, const float* __restrict__ resid)
{
    __shared__ alignas(16) float As[16][128];
    __shared__ alignas(16) float Ws[16][128];
    const int tid = threadIdx.x;
    const int m0 = blockIdx.y * 128;
    const int n0 = blockIdx.x * 128;
    const int tx = tid & 15;
    const int ty = tid >> 4;

    // each thread loads 2 float4 from A and 2 from W per K-tile
    int ar[2], ac4[2];
    const float* Ap[2];
    const float* Wp[2];
    bool wv[2];
    #pragma unroll
    for (int i = 0; i < 2; i++) {
        int f = tid * 2 + i;
        int row = f >> 2;
        int c4  = (f & 3) * 4;
        ar[i] = row; ac4[i] = c4;
        int arow = m0 + row;
        if (flipA) arow = flip_row(arow, lengths);
        Ap[i] = A + (size_t)arow * K + c4;
        int wrow = n0 + row;
        wv[i] = (wrow < N);
        Wp[i] = W + (size_t)(wv[i] ? wrow : 0) * K + c4;
    }

    float acc[8][8];
    #pragma unroll
    for (int i = 0; i < 8; i++)
        #pragma unroll
        for (int j = 0; j < 8; j++) acc[i][j] = 0.f;

    for (int k0 = 0; k0 < K; k0 += 16) {
        float4 av[2], wvv[2];
        #pragma unroll
        for (int i = 0; i < 2; i++) {
            av[i]  = *(const float4*)(Ap[i] + k0);
            wvv[i] = wv[i] ? *(const float4*)(Wp[i] + k0) : make_float4(0.f,0.f,0.f,0.f);
        }
        __syncthreads();
        #pragma unroll
        for (int i = 0; i < 2; i++) {
            As[ac4[i]+0][ar[i]] = av[i].x;
            As[ac4[i]+1][ar[i]] = av[i].y;
            As[ac4[i]+2][ar[i]] = av[i].z;
            As[ac4[i]+3][ar[i]] = av[i].w;
            Ws[ac4[i]+0][ar[i]] = wvv[i].x;
            Ws[ac4[i]+1][ar[i]] = wvv[i].y;
            Ws[ac4[i]+2][ar[i]] = wvv[i].z;
            Ws[ac4[i]+3][ar[i]] = wvv[i].w;
        }
        __syncthreads();
        #pragma unroll
        for (int k = 0; k < 16; k++) {
            float4 a0 = *(const float4*)&As[k][ty*4];
            float4 a1 = *(const float4*)&As[k][64 + ty*4];
            float4 b0 = *(const float4*)&Ws[k][tx*4];
            float4 b1 = *(const float4*)&Ws[k][64 + tx*4];
            float a[8]  = {a0.x,a0.y,a0.z,a0.w,a1.x,a1.y,a1.z,a1.w};
            float bb[8] = {b0.x,b0.y,b0.z,b0.w,b1.x,b1.y,b1.z,b1.w};
            #pragma unroll
            for (int i = 0; i < 8; i++)
                #pragma unroll
                for (int j = 0; j < 8; j++)
                    acc[i][j] = fmaf(a[i], bb[j], acc[i][j]);
        }
    }

    #pragma unroll
    for (int i = 0; i < 8; i++) {
        int mrow = m0 + ((i < 4) ? (ty*4 + i) : (64 + ty*4 + i - 4));
        int crow = flipC ? flip_row(mrow, lengths) : mrow;
        float* Crow = C + (size_t)crow * ldc + ccol;
        const float* Rrow = resid ? (resid + (size_t)mrow * D_MODEL) : nullptr;
        #pragma unroll
        for (int jh = 0; jh < 2; jh++) {
            int nn = n0 + jh*64 + tx*4;
            if (nn < N) {
                float4 v;
                v.x = acc[i][jh*4+0]; v.y = acc[i][jh*4+1];
                v.z = acc[i][jh*4+2]; v.w = acc[i][jh*4+3];
                if (bias)  { v.x += bias[nn]; v.y += bias[nn+1]; v.z += bias[nn+2]; v.w += bias[nn+3]; }
                if (Rrow)  { float4 r = *(const float4*)(Rrow + nn);
                             v.x += r.x; v.y += r.y; v.z += r.z; v.w += r.w; }
                *(float4*)(Crow + nn) = v;
            }
        }
    }
}

// causal depthwise conv (width 4) + silu on the xBC slice of zxbcdt
__global__ __launch_bounds__(256)
void conv_silu_kernel(const float* __restrict__ zx, const float* __restrict__ cw,
                      const float* __restrict__ cb, float* __restrict__ xBC)
{
    const int c = blockIdx.x * 256 + threadIdx.x;
    const int row = blockIdx.y;
    if (c >= CONV_DIM) return;
    const int t = row & (SEQLEN - 1);
    float acc = cb[c];
    #pragma unroll
    for (int k = 0; k < D_CONV; k++) {
        int tt = t + k - (D_CONV - 1);
        if (tt >= 0)
            acc = fmaf(zx[(size_t)(row + k - (D_CONV-1)) * D_IN_PROJ + D_INNER + c],
                       cw[c * D_CONV + k], acc);
    }
    xBC[(size_t)row * CONV_DIM + c] = acc / (1.f + expf(-acc));
}

// dt = softplus(dt_raw + bias), dA = exp(dt * (-exp(A_log)))
__global__ __launch_bounds__(256)
void dt_kernel(const float* __restrict__ zx, const float* __restrict__ dt_bias,
               const float* __restrict__ A_log, float* __restrict__ dt,
               float* __restrict__ dAe)
{
    int i = blockIdx.x * 256 + threadIdx.x;
    if (i >= NROWS * NHEADS) return;
    int row = i / NHEADS, h = i - row * NHEADS;
    float v = zx[(size_t)row * D_IN_PROJ + (D_INNER + CONV_DIM) + h] + dt_bias[h];
    float sp = (v > 20.f) ? v : log1pf(expf(v));
    float A = -expf(A_log[h]);
    dt[i] = sp;
    dAe[i] = expf(sp * A);
}

// sequential SSM scan: grid (B*NHEADS, 4 p-splits), 256 threads
// thread (pl = tid>>4, nq = tid&15) owns state h[p = pbase+pl][n = nq*4 .. +3]
__global__ __launch_bounds__(256)
void scan_kernel(const float* __restrict__ xBC, const float* __restrict__ dt,
                 const float* __restrict__ dA, const float* __restrict__ Dp,
                 float* __restrict__ y)
{
    const int bh = blockIdx.x;            // 0..95
    const int b = bh / NHEADS, h = bh - b * NHEADS;
    const int pbase = blockIdx.y * 16;
    const int tid = threadIdx.x;
    const int pl = tid >> 4;
    const int p  = pbase + pl;
    const int nq = tid & 15;

    __shared__ alignas(16) float sx[2][16];
    __shared__ alignas(16) float sB[2][64];
    __shared__ alignas(16) float sC[2][64];
    __shared__ float sm[2][2];

    float hreg[4] = {0.f, 0.f, 0.f, 0.f};
    const size_t rowbase = (size_t)b * SEQLEN;
    const float Dph = Dp[h];

    {   // preload t=0
        const float* r = xBC + rowbase * CONV_DIM;
        if (tid < 16)                       sx[0][tid]     = r[h*HEADDIM + pbase + tid];
        else if (tid >= 64 && tid < 128)    sB[0][tid-64]  = r[D_INNER + (tid-64)];
        else if (tid >= 128 && tid < 192)   sC[0][tid-128] = r[D_INNER + D_STATE + (tid-128)];
        else if (tid == 192)                sm[0][0]       = dt[rowbase*NHEADS + h];
        else if (tid == 193)                sm[0][1]       = dA[rowbase*NHEADS + h];
    }
    __syncthreads();

    for (int t = 0; t < SEQLEN; t++) {
        const int cb = t & 1, nb = cb ^ 1;
        float pre = 0.f;
        if (t + 1 < SEQLEN) {
            const float* r = xBC + (rowbase + t + 1) * CONV_DIM;
            if (tid < 16)                     pre = r[h*HEADDIM + pbase + tid];
            else if (tid >= 64 && tid < 128)  pre = r[D_INNER + (tid-64)];
            else if (tid >= 128 && tid < 192) pre = r[D_INNER + D_STATE + (tid-128)];
            else if (tid == 192)              pre = dt[(rowbase+t+1)*NHEADS + h];
            else if (tid == 193)              pre = dA[(rowbase+t+1)*NHEADS + h];
        }
        const float dtv = sm[cb][0];
        const float dav = sm[cb][1];
        const float xv  = sx[cb][pl];
        const float dtx = dtv * xv;
        const float4 bv = *(const float4*)&sB[cb][nq*4];
        const float4 cv = *(const float4*)&sC[cb][nq*4];
        hreg[0] = fmaf(hreg[0], dav, dtx * bv.x);
        hreg[1] = fmaf(hreg[1], dav, dtx * bv.y);
        hreg[2] = fmaf(hreg[2], dav, dtx * bv.z);
        hreg[3] = fmaf(hreg[3], dav, dtx * bv.w);
        float acc = hreg[0]*cv.x + hreg[1]*cv.y + hreg[2]*cv.z + hreg[3]*cv.w;
        acc += __shfl_xor(acc, 1);
        acc += __shfl_xor(acc, 2);
        acc += __shfl_xor(acc, 4);
        acc += __shfl_xor(acc, 8);
        if (nq == 0)
            y[(rowbase + t) * D_INNER + h*HEADDIM + p] = acc + Dph * xv;
        if (t + 1 < SEQLEN) {
            if (tid < 16)                     sx[nb][tid]     = pre;
            else if (tid >= 64 && tid < 128)  sB[nb][tid-64]  = pre;
            else if (tid >= 128 && tid < 192) sC[nb][tid-128] = pre;
            else if (tid == 192)              sm[nb][0]       = pre;
            else if (tid == 193)              sm[nb][1]       = pre;
        }
        __syncthreads();
    }
}

// y = y * silu(z); y = y * rsqrt(mean(y^2)+1e-5) * norm_w   (in place, per row)
__global__ __launch_bounds__(256)
void gate_rmsnorm_kernel(float* __restrict__ y, const float* __restrict__ zx,
                         const float* __restrict__ norm_w)
{
    const int row = blockIdx.x;
    const float* z = zx + (size_t)row * D_IN_PROJ;
    float* yr = y + (size_t)row * D_INNER;
    const int tid = threadIdx.x;
    float g[6];
    float ss = 0.f;
    #pragma unroll
    for (int i = 0; i < 6; i++) {
        int e = tid + i * 256;
        float zv = z[e];
        float gv = yr[e] * (zv / (1.f + expf(-zv)));
        g[i] = gv;
        ss = fmaf(gv, gv, ss);
    }
    #pragma unroll
    for (int o = 32; o > 0; o >>= 1) ss += __shfl_xor(ss, o);
    __shared__ float red[4];
    if ((tid & 63) == 0) red[tid >> 6] = ss;
    __syncthreads();
    float tot = red[0] + red[1] + red[2] + red[3];
    float scale = rsqrtf(tot * (1.f / D_INNER) + 1e-5f);
    #pragma unroll
    for (int i = 0; i < 6; i++) {
        int e = tid + i * 256;
        yr[e] = g[i] * scale * norm_w[e];
    }
}

__global__ __launch_bounds__(256)
void layernorm_kernel(const float* __restrict__ r, const float* __restrict__ gam,
                      const float* __restrict__ bet, float* __restrict__ out)
{
    const int row = blockIdx.x;
    const float* rr = r + (size_t)row * D_MODEL;
    const int tid = threadIdx.x;
    float v[3];
    float s = 0.f, s2 = 0.f;
    #pragma unroll
    for (int i = 0; i < 3; i++) {
        v[i] = rr[tid + i * 256];
        s += v[i];
        s2 = fmaf(v[i], v[i], s2);
    }
    #pragma unroll
    for (int o = 32; o > 0; o >>= 1) { s += __shfl_xor(s, o); s2 += __shfl_xor(s2, o); }
    __shared__ float rs[4], rs2[4];
    if ((tid & 63) == 0) { rs[tid >> 6] = s; rs2[tid >> 6] = s2; }
    __syncthreads();
    float S  = rs[0] + rs[1] + rs[2] + rs[3];
    float S2 = rs2[0] + rs2[1] + rs2[2] + rs2[3];
    float mu  = S * (1.f / D_MODEL);
    float var = S2 * (1.f / D_MODEL) - mu * mu;
    float inv = rsqrtf(var + 1e-5f);
    #pragma unroll
    for (int i = 0; i < 3; i++) {
        int e = tid + i * 256;
        out[(size_t)row * D_MODEL + e] = (v[i] - mu) * inv * gam[e] + bet[e];
    }
}

extern "C" void kernel_launch(void* const* d_in, const int* in_sizes, int n_in,
                              void* d_out, int out_size, void* d_ws, size_t ws_size,
                              hipStream_t stream)
{
    const float* x        = (const float*)d_in[0];
    const int*   lengths  = (const int*)d_in[1];
    const float* in_w[2]    = {(const float*)d_in[2],  (const float*)d_in[10]};
    const float* conv_w[2]  = {(const float*)d_in[3],  (const float*)d_in[11]};
    const float* conv_b[2]  = {(const float*)d_in[4],  (const float*)d_in[12]};
    const float* dt_bias[2] = {(const float*)d_in[5],  (const float*)d_in[13]};
    const float* A_log[2]   = {(const float*)d_in[6],  (const float*)d_in[14]};
    const float* Dp[2]      = {(const float*)d_in[7],  (const float*)d_in[15]};
    const float* norm_w[2]  = {(const float*)d_in[8],  (const float*)d_in[16]};
    const float* out_w[2]   = {(const float*)d_in[9],  (const float*)d_in[17]};
    const float* op_w = (const float*)d_in[18];
    const float* op_b = (const float*)d_in[19];
    const float* ln_g = (const float*)d_in[20];
    const float* ln_b = (const float*)d_in[21];
    float* outp = (float*)d_out;

    // workspace layout (262.4 MB total)
    float* zx   = (float*)d_ws;                               // 8192*3224
    float* xbc  = zx  + (size_t)NROWS * D_IN_PROJ;            // 8192*1664
    float* dtb  = xbc + (size_t)NROWS * CONV_DIM;             // 8192*24
    float* dab  = dtb + (size_t)NROWS * NHEADS;               // 8192*24
    float* ybuf = dab + (size_t)NROWS * NHEADS;               // 8192*1536
    float* comb = ybuf + (size_t)NROWS * D_INNER;             // 8192*1536
    float* rbuf = zx;  // reuse zx for the pre-LN residual (zx dead by then)

    size_t need = ((size_t)NROWS * D_IN_PROJ + (size_t)NROWS * CONV_DIM +
                   2 * (size_t)NROWS * NHEADS + 2 * (size_t)NROWS * D_INNER) * sizeof(float);
    if (ws_size < need) return;  // workspace too small; validation will flag

    for (int dir = 0; dir < 2; dir++) {
        // 1. in_proj:  zx[m, :] = x[flip?(m), :] @ in_w^T   (M=8192,N=3224,K=768)
        sgemm_nt<<<dim3(26, 64), 256, 0, stream>>>(
            x, in_w[dir], zx, D_IN_PROJ, D_MODEL, D_IN_PROJ, 0,
            lengths, dir, 0, nullptr, nullptr);
        // 2. causal conv + silu  -> xbc
        conv_silu_kernel<<<dim3(7, NROWS), 256, 0, stream>>>(zx, conv_w[dir], conv_b[dir], xbc);
        // 3. dt / dA precompute
        dt_kernel<<<(NROWS*NHEADS + 255)/256, 256, 0, stream>>>(zx, dt_bias[dir], A_log[dir], dtb, dab);
        // 4. sequential scan -> ybuf
        scan_kernel<<<dim3(BATCH*NHEADS, 4), 256, 0, stream>>>(xbc, dtb, dab, Dp[dir], ybuf);
        // 5. gate with silu(z) + RMSNorm (in place)
        gate_rmsnorm_kernel<<<NROWS, 256, 0, stream>>>(ybuf, zx, norm_w[dir]);
        // 6. out_proj -> comb[:, dir*768 : dir*768+768], rows flipped for bwd
        sgemm_nt<<<dim3(6, 64), 256, 0, stream>>>(
            ybuf, out_w[dir], comb, D_MODEL, D_INNER, 2*D_MODEL, dir*D_MODEL,
            lengths, 0, dir, nullptr, nullptr);
    }

    // final: rbuf = comb @ op_w^T + op_b + x   (M=8192,N=768,K=1536)
    sgemm_nt<<<dim3(6, 64), 256, 0, stream>>>(
        comb, op_w, rbuf, D_MODEL, 2*D_MODEL, D_MODEL, 0,
        lengths, 0, 0, op_b, x);
    // layernorm -> out
    layernorm_kernel<<<NROWS, 256, 0, stream>>>(rbuf, ln_g, ln_b, outp);
}

// Round 4
// 2915.752 us; speedup vs baseline: 1.9758x; 1.9758x over previous
//
#include <hip/hip_runtime.h>
#include <cstdint>
#include <cstddef>

#define D_MODEL   768
#define D_STATE   64
#define D_INNER   1536
#define HEADDIM   64
#define NHEADS    24
#define D_CONV    4
#define CONV_DIM  1664      // D_INNER + 2*D_STATE
#define D_IN_PROJ 3224      // 2*D_INNER + 2*D_STATE + NHEADS
#define BATCH     4
#define SEQLEN    2048
#define NROWS     (BATCH*SEQLEN)   // 8192
#define NSEG      8
#define SEGLEN    256              // SEQLEN / NSEG

__device__ __forceinline__ int flip_row(int m, const int* __restrict__ lengths) {
    int b = m >> 11;                 // SEQLEN = 2048
    int t = m & (SEQLEN - 1);
    int len = lengths[b];
    int ft = (t < len) ? (len - 1 - t) : t;
    return (b << 11) | ft;
}

// C[m, ccol+n] (+bias[n] +resid[m]) = sum_k A[m,k] * W[n,k]
// A: [8192, K] row-major (rows optionally flip-indexed on read)
// W: [N, K] row-major
// 128x128 tile, BK=16, 256 threads, 8x8 microtile per thread.
// If split!=0, the output columns are routed to three separate buffers:
//   n < 1536        -> Cz   [row][1536]
//   1536 <= n <3200 -> Cxbc [row][1664]   (col n-1536)
//   n >= 3200       -> Cdt  [row][24]     (col n-3200)
__global__ __launch_bounds__(256, 2)
void sgemm_nt(const float* __restrict__ A, const float* __restrict__ W,
              float* __restrict__ C, int N, int K, int ldc, int ccol,
              const int* __restrict__ lengths, int flipA, int flipC,
              const float* __restrict__ bias, const float* __restrict__ resid,
              int split, float* __restrict__ Cz, float* __restrict__ Cxbc,
              float* __restrict__ Cdt)
{
    __shared__ alignas(16) float As[16][128];
    __shared__ alignas(16) float Ws[16][128];
    const int tid = threadIdx.x;
    const int m0 = blockIdx.y * 128;
    const int n0 = blockIdx.x * 128;
    const int tx = tid & 15;
    const int ty = tid >> 4;

    int ar[2], ac4[2];
    const float* Ap[2];
    const float* Wp[2];
    bool wv[2];
    #pragma unroll
    for (int i = 0; i < 2; i++) {
        int f = tid * 2 + i;
        int row = f >> 2;
        int c4  = (f & 3) * 4;
        ar[i] = row; ac4[i] = c4;
        int arow = m0 + row;
        if (flipA) arow = flip_row(arow, lengths);
        Ap[i] = A + (size_t)arow * K + c4;
        int wrow = n0 + row;
        wv[i] = (wrow < N);
        Wp[i] = W + (size_t)(wv[i] ? wrow : 0) * K + c4;
    }

    float acc[8][8];
    #pragma unroll
    for (int i = 0; i < 8; i++)
        #pragma unroll
        for (int j = 0; j < 8; j++) acc[i][j] = 0.f;

    for (int k0 = 0; k0 < K; k0 += 16) {
        float4 av[2], wvv[2];
        #pragma unroll
        for (int i = 0; i < 2; i++) {
            av[i]  = *(const float4*)(Ap[i] + k0);
            wvv[i] = wv[i] ? *(const float4*)(Wp[i] + k0) : make_float4(0.f,0.f,0.f,0.f);
        }
        __syncthreads();
        #pragma unroll
        for (int i = 0; i < 2; i++) {
            As[ac4[i]+0][ar[i]] = av[i].x;
            As[ac4[i]+1][ar[i]] = av[i].y;
            As[ac4[i]+2][ar[i]] = av[i].z;
            As[ac4[i]+3][ar[i]] = av[i].w;
            Ws[ac4[i]+0][ar[i]] = wvv[i].x;
            Ws[ac4[i]+1][ar[i]] = wvv[i].y;
            Ws[ac4[i]+2][ar[i]] = wvv[i].z;
            Ws[ac4[i]+3][ar[i]] = wvv[i].w;
        }
        __syncthreads();
        #pragma unroll
        for (int k = 0; k < 16; k++) {
            float4 a0 = *(const float4*)&As[k][ty*4];
            float4 a1 = *(const float4*)&As[k][64 + ty*4];
            float4 b0 = *(const float4*)&Ws[k][tx*4];
            float4 b1 = *(const float4*)&Ws[k][64 + tx*4];
            float a[8]  = {a0.x,a0.y,a0.z,a0.w,a1.x,a1.y,a1.z,a1.w};
            float bb[8] = {b0.x,b0.y,b0.z,b0.w,b1.x,b1.y,b1.z,b1.w};
            #pragma unroll
            for (int i = 0; i < 8; i++)
                #pragma unroll
                for (int j = 0; j < 8; j++)
                    acc[i][j] = fmaf(a[i], bb[j], acc[i][j]);
        }
    }

    #pragma unroll
    for (int i = 0; i < 8; i++) {
        int mrow = m0 + ((i < 4) ? (ty*4 + i) : (64 + ty*4 + i - 4));
        int crow = flipC ? flip_row(mrow, lengths) : mrow;
        const float* Rrow = resid ? (resid + (size_t)mrow * D_MODEL) : nullptr;
        #pragma unroll
        for (int jh = 0; jh < 2; jh++) {
            int nn = n0 + jh*64 + tx*4;
            if (nn < N) {
                float4 v;
                v.x = acc[i][jh*4+0]; v.y = acc[i][jh*4+1];
                v.z = acc[i][jh*4+2]; v.w = acc[i][jh*4+3];
                if (bias)  { v.x += bias[nn]; v.y += bias[nn+1]; v.z += bias[nn+2]; v.w += bias[nn+3]; }
                if (Rrow)  { float4 r = *(const float4*)(Rrow + nn);
                             v.x += r.x; v.y += r.y; v.z += r.z; v.w += r.w; }
                if (split) {
                    if (nn < D_INNER)
                        *(float4*)(Cz + (size_t)crow * D_INNER + nn) = v;
                    else if (nn < D_INNER + CONV_DIM)
                        *(float4*)(Cxbc + (size_t)crow * CONV_DIM + (nn - D_INNER)) = v;
                    else
                        *(float4*)(Cdt + (size_t)crow * NHEADS + (nn - D_INNER - CONV_DIM)) = v;
                } else {
                    *(float4*)(C + (size_t)crow * ldc + ccol + nn) = v;
                }
            }
        }
    }
}

// causal depthwise conv (width 4) + silu:  xbcr [row][CONV_DIM] -> xbc
__global__ __launch_bounds__(256)
void conv_silu_kernel(const float* __restrict__ xbcr, const float* __restrict__ cw,
                      const float* __restrict__ cb, float* __restrict__ xBC)
{
    const int c = blockIdx.x * 256 + threadIdx.x;
    const int row = blockIdx.y;
    if (c >= CONV_DIM) return;
    const int t = row & (SEQLEN - 1);
    float acc = cb[c];
    #pragma unroll
    for (int k = 0; k < D_CONV; k++) {
        int tt = t + k - (D_CONV - 1);
        if (tt >= 0)
            acc = fmaf(xbcr[(size_t)(row + k - (D_CONV-1)) * CONV_DIM + c],
                       cw[c * D_CONV + k], acc);
    }
    xBC[(size_t)row * CONV_DIM + c] = acc / (1.f + expf(-acc));
}

// dt = softplus(dt_raw + bias), dA = exp(dt * (-exp(A_log)))
__global__ __launch_bounds__(256)
void dt_kernel(const float* __restrict__ dtr, const float* __restrict__ dt_bias,
               const float* __restrict__ A_log, float* __restrict__ dt,
               float* __restrict__ dAe)
{
    int i = blockIdx.x * 256 + threadIdx.x;
    if (i >= NROWS * NHEADS) return;
    int h = i % NHEADS;
    float v = dtr[i] + dt_bias[h];
    float sp = (v > 20.f) ? v : log1pf(expf(v));
    float A = -expf(A_log[h]);
    dt[i] = sp;
    dAe[i] = expf(sp * A);
}

// Pass 1: segmented barrier-free scan.
// grid (96 bh, 8 seg, 16 pg), 64 threads (one wave).
// lane: pl = lane>>4 (p = pg*4+pl), nq = lane&15 (n = nq*4 .. +3).
// Scans its 256-row segment starting from h=0; writes partial y (+D*x),
// per-step cumulative decay dcum (pg==0 only), and final local state hloc.
__global__ __launch_bounds__(64)
void scan_seg_kernel(const float* __restrict__ xbc, const float* __restrict__ dtb,
                     const float* __restrict__ dab, const float* __restrict__ Dp,
                     float* __restrict__ y, float* __restrict__ hloc,
                     float* __restrict__ dcum)
{
    const int bh = blockIdx.x;
    const int b = bh / NHEADS, h = bh - b * NHEADS;
    const int s  = blockIdx.y;
    const int pg = blockIdx.z;
    const int lane = threadIdx.x;
    const int pl = lane >> 4, nq = lane & 15;
    const int p  = pg * 4 + pl;
    const int row0 = b * SEQLEN + s * SEGLEN;
    const float Dph = Dp[h];

    const float* xp = xbc + (size_t)row0 * CONV_DIM + h * HEADDIM + p;
    const float* Bp = xbc + (size_t)row0 * CONV_DIM + D_INNER + nq * 4;
    const float* Cp = Bp + D_STATE;
    const float* mp = dtb + (size_t)row0 * NHEADS + h;
    const float* ap = dab + (size_t)row0 * NHEADS + h;
    float* yp = y + (size_t)row0 * D_INNER + h * HEADDIM + p;
    float* dc = dcum + (size_t)row0 * NHEADS + h;

    float h0 = 0.f, h1 = 0.f, h2 = 0.f, h3 = 0.f, cumA = 1.f;

    float xv = *xp;
    float4 Bv = *(const float4*)Bp;
    float4 Cv = *(const float4*)Cp;
    float dtv = *mp, dav = *ap;

    for (int i = 0; i < SEGLEN; i++) {
        float xn = 0.f, dtn = 0.f, dan = 0.f;
        float4 Bn = make_float4(0,0,0,0), Cn = make_float4(0,0,0,0);
        if (i + 1 < SEGLEN) {
            xp += CONV_DIM; Bp += CONV_DIM; Cp += CONV_DIM; mp += NHEADS; ap += NHEADS;
            xn = *xp; Bn = *(const float4*)Bp; Cn = *(const float4*)Cp;
            dtn = *mp; dan = *ap;
        }
        const float dtx = dtv * xv;
        h0 = fmaf(h0, dav, dtx * Bv.x);
        h1 = fmaf(h1, dav, dtx * Bv.y);
        h2 = fmaf(h2, dav, dtx * Bv.z);
        h3 = fmaf(h3, dav, dtx * Bv.w);
        float acc = h0*Cv.x + h1*Cv.y + h2*Cv.z + h3*Cv.w;
        acc += __shfl_xor(acc, 1);
        acc += __shfl_xor(acc, 2);
        acc += __shfl_xor(acc, 4);
        acc += __shfl_xor(acc, 8);
        cumA *= dav;
        if (nq == 0) *yp = acc + Dph * xv;
        if (pg == 0 && lane == 0) *dc = cumA;
        yp += D_INNER; dc += NHEADS;
        xv = xn; Bv = Bn; Cv = Cn; dtv = dtn; dav = dan;
    }
    *(float4*)(hloc + ((size_t)(bh * NSEG + s)) * 4096 + p * 64 + nq * 4) =
        make_float4(h0, h1, h2, h3);
}

// Pass 2: sequential fold of segment states. grid 96 blocks x 256 threads.
// h_in[0] = 0 ; h_in[s] = hloc[s-1] + P[s-1] * h_in[s-1]
__global__ __launch_bounds__(256)
void combine_kernel(const float* __restrict__ hloc, const float* __restrict__ dcum,
                    float* __restrict__ hin)
{
    const int bh = blockIdx.x;
    const int b = bh / NHEADS, h = bh - b * NHEADS;
    const int tid = threadIdx.x;          // each thread owns 16 floats
    float4 hv[4];
    #pragma unroll
    for (int j = 0; j < 4; j++) hv[j] = make_float4(0,0,0,0);
    for (int s = 0; s < NSEG; s++) {
        float* out = hin + (size_t)(bh * NSEG + s) * 4096 + tid * 16;
        #pragma unroll
        for (int j = 0; j < 4; j++) *(float4*)(out + j*4) = hv[j];
        if (s < NSEG - 1) {
            float P = dcum[((size_t)(b * SEQLEN + s * SEGLEN + SEGLEN - 1)) * NHEADS + h];
            const float* hl = hloc + (size_t)(bh * NSEG + s) * 4096 + tid * 16;
            #pragma unroll
            for (int j = 0; j < 4; j++) {
                float4 lv = *(const float4*)(hl + j*4);
                hv[j].x = fmaf(hv[j].x, P, lv.x);
                hv[j].y = fmaf(hv[j].y, P, lv.y);
                hv[j].z = fmaf(hv[j].z, P, lv.z);
                hv[j].w = fmaf(hv[j].w, P, lv.w);
            }
        }
    }
}

// Pass 3: y[t] += dcum[t] * (C[t] . h_in[seg(t)])   for segments 1..7
// grid (96 bh, 7), 256 threads = 4 row-groups x 64 p-lanes.
__global__ __launch_bounds__(256)
void corr_kernel(const float* __restrict__ xbc, const float* __restrict__ dcum,
                 const float* __restrict__ hin, float* __restrict__ y)
{
    const int bh = blockIdx.x;
    const int b = bh / NHEADS, h = bh - b * NHEADS;
    const int s = blockIdx.y + 1;
    const int tid = threadIdx.x;
    const int rg = tid >> 6;          // 0..3
    const int p  = tid & 63;

    const float* hp = hin + (size_t)(bh * NSEG + s) * 4096 + p * 64;
    float4 H[16];
    #pragma unroll
    for (int j = 0; j < 16; j++) H[j] = *(const float4*)(hp + j * 4);

    const int row0 = b * SEQLEN + s * SEGLEN;
    for (int i = rg; i < SEGLEN; i += 4) {
        const size_t row = row0 + i;
        const float* Crow = xbc + row * CONV_DIM + D_INNER + D_STATE;
        const float cA = dcum[row * NHEADS + h];
        float acc = 0.f;
        #pragma unroll
        for (int j = 0; j < 16; j++) {
            float4 c = *(const float4*)(Crow + j * 4);
            acc += H[j].x*c.x + H[j].y*c.y + H[j].z*c.z + H[j].w*c.w;
        }
        y[row * D_INNER + h * HEADDIM + p] += cA * acc;
    }
}

// y = y * silu(z); y = y * rsqrt(mean(y^2)+1e-5) * norm_w   (in place, per row)
__global__ __launch_bounds__(256)
void gate_rmsnorm_kernel(float* __restrict__ y, const float* __restrict__ z,
                         const float* __restrict__ norm_w)
{
    const int row = blockIdx.x;
    const float* zr = z + (size_t)row * D_INNER;
    float* yr = y + (size_t)row * D_INNER;
    const int tid = threadIdx.x;
    float g[6];
    float ss = 0.f;
    #pragma unroll
    for (int i = 0; i < 6; i++) {
        int e = tid + i * 256;
        float zv = zr[e];
        float gv = yr[e] * (zv / (1.f + expf(-zv)));
        g[i] = gv;
        ss = fmaf(gv, gv, ss);
    }
    #pragma unroll
    for (int o = 32; o > 0; o >>= 1) ss += __shfl_xor(ss, o);
    __shared__ float red[4];
    if ((tid & 63) == 0) red[tid >> 6] = ss;
    __syncthreads();
    float tot = red[0] + red[1] + red[2] + red[3];
    float scale = rsqrtf(tot * (1.f / D_INNER) + 1e-5f);
    #pragma unroll
    for (int i = 0; i < 6; i++) {
        int e = tid + i * 256;
        yr[e] = g[i] * scale * norm_w[e];
    }
}

__global__ __launch_bounds__(256)
void layernorm_kernel(const float* __restrict__ r, const float* __restrict__ gam,
                      const float* __restrict__ bet, float* __restrict__ out)
{
    const int row = blockIdx.x;
    const float* rr = r + (size_t)row * D_MODEL;
    const int tid = threadIdx.x;
    float v[3];
    float s = 0.f, s2 = 0.f;
    #pragma unroll
    for (int i = 0; i < 3; i++) {
        v[i] = rr[tid + i * 256];
        s += v[i];
        s2 = fmaf(v[i], v[i], s2);
    }
    #pragma unroll
    for (int o = 32; o > 0; o >>= 1) { s += __shfl_xor(s, o); s2 += __shfl_xor(s2, o); }
    __shared__ float rs[4], rs2[4];
    if ((tid & 63) == 0) { rs[tid >> 6] = s; rs2[tid >> 6] = s2; }
    __syncthreads();
    float S  = rs[0] + rs[1] + rs[2] + rs[3];
    float S2 = rs2[0] + rs2[1] + rs2[2] + rs2[3];
    float mu  = S * (1.f / D_MODEL);
    float var = S2 * (1.f / D_MODEL) - mu * mu;
    float inv = rsqrtf(var + 1e-5f);
    #pragma unroll
    for (int i = 0; i < 3; i++) {
        int e = tid + i * 256;
        out[(size_t)row * D_MODEL + e] = (v[i] - mu) * inv * gam[e] + bet[e];
    }
}

extern "C" void kernel_launch(void* const* d_in, const int* in_sizes, int n_in,
                              void* d_out, int out_size, void* d_ws, size_t ws_size,
                              hipStream_t stream)
{
    const float* x        = (const float*)d_in[0];
    const int*   lengths  = (const int*)d_in[1];
    const float* in_w[2]    = {(const float*)d_in[2],  (const float*)d_in[10]};
    const float* conv_w[2]  = {(const float*)d_in[3],  (const float*)d_in[11]};
    const float* conv_b[2]  = {(const float*)d_in[4],  (const float*)d_in[12]};
    const float* dt_bias[2] = {(const float*)d_in[5],  (const float*)d_in[13]};
    const float* A_log[2]   = {(const float*)d_in[6],  (const float*)d_in[14]};
    const float* Dp[2]      = {(const float*)d_in[7],  (const float*)d_in[15]};
    const float* norm_w[2]  = {(const float*)d_in[8],  (const float*)d_in[16]};
    const float* out_w[2]   = {(const float*)d_in[9],  (const float*)d_in[17]};
    const float* op_w = (const float*)d_in[18];
    const float* op_b = (const float*)d_in[19];
    const float* ln_g = (const float*)d_in[20];
    const float* ln_b = (const float*)d_in[21];
    float* outp = (float*)d_out;

    // workspace layout (262.4 MB, same footprint as R1)
    float* z    = (float*)d_ws;                               // 8192*1536
    float* xbcr = z    + (size_t)NROWS * D_INNER;             // 8192*1664
    float* dtr  = xbcr + (size_t)NROWS * CONV_DIM;            // 8192*24
    float* dtb  = dtr  + (size_t)NROWS * NHEADS;              // 8192*24
    float* dab  = dtb  + (size_t)NROWS * NHEADS;              // 8192*24
    float* xbc  = dab  + (size_t)NROWS * NHEADS;              // 8192*1664
    float* ybuf = xbc  + (size_t)NROWS * CONV_DIM;            // 8192*1536
    float* comb = ybuf + (size_t)NROWS * D_INNER;             // 8192*1536
    // xbcr is dead after conv+dt; reuse its space for scan scratch:
    float* hloc = xbcr;                                       // 768*4096
    float* hin  = hloc + (size_t)BATCH*NHEADS*NSEG*4096;      // 768*4096
    float* dcum = hin  + (size_t)BATCH*NHEADS*NSEG*4096;      // 8192*24
    // z region is dead after both dirs' gate; reuse for pre-LN residual:
    float* rbuf = z;

    size_t need = ((size_t)NROWS * (D_INNER + CONV_DIM + 3*NHEADS + CONV_DIM +
                                    D_INNER + D_INNER)) * sizeof(float);
    if (ws_size < need) return;

    for (int dir = 0; dir < 2; dir++) {
        // 1. in_proj (split outputs):  [z | xbcr | dtr] = x[flip?] @ in_w^T
        sgemm_nt<<<dim3(26, 64), 256, 0, stream>>>(
            x, in_w[dir], nullptr, D_IN_PROJ, D_MODEL, 0, 0,
            lengths, dir, 0, nullptr, nullptr, 1, z, xbcr, dtr);
        // 2. causal conv + silu  -> xbc
        conv_silu_kernel<<<dim3(7, NROWS), 256, 0, stream>>>(xbcr, conv_w[dir], conv_b[dir], xbc);
        // 3. dt / dA precompute
        dt_kernel<<<(NROWS*NHEADS + 255)/256, 256, 0, stream>>>(dtr, dt_bias[dir], A_log[dir], dtb, dab);
        // 4a. segmented scan pass 1 (xbcr now dead -> hloc/hin/dcum live there)
        scan_seg_kernel<<<dim3(BATCH*NHEADS, NSEG, 16), 64, 0, stream>>>(
            xbc, dtb, dab, Dp[dir], ybuf, hloc, dcum);
        // 4b. combine segment states
        combine_kernel<<<BATCH*NHEADS, 256, 0, stream>>>(hloc, dcum, hin);
        // 4c. cross-segment correction
        corr_kernel<<<dim3(BATCH*NHEADS, NSEG-1), 256, 0, stream>>>(xbc, dcum, hin, ybuf);
        // 5. gate with silu(z) + RMSNorm (in place)
        gate_rmsnorm_kernel<<<NROWS, 256, 0, stream>>>(ybuf, z, norm_w[dir]);
        // 6. out_proj -> comb[:, dir*768 .. ], rows flipped for bwd
        sgemm_nt<<<dim3(6, 64), 256, 0, stream>>>(
            ybuf, out_w[dir], comb, D_MODEL, D_INNER, 2*D_MODEL, dir*D_MODEL,
            lengths, 0, dir, nullptr, nullptr, 0, nullptr, nullptr, nullptr);
    }

    // final: rbuf = comb @ op_w^T + op_b + x   (M=8192,N=768,K=1536)
    sgemm_nt<<<dim3(6, 64), 256, 0, stream>>>(
        comb, op_w, rbuf, D_MODEL, 2*D_MODEL, D_MODEL, 0,
        lengths, 0, 0, op_b, x, 0, nullptr, nullptr, nullptr);
    // layernorm -> out
    layernorm_kernel<<<NROWS, 256, 0, stream>>>(rbuf, ln_g, ln_b, outp);
}

// Round 5
// 1639.077 us; speedup vs baseline: 3.5148x; 1.7789x over previous
//
#include <hip/hip_runtime.h>
#include <cstdint>
#include <cstddef>

#define D_MODEL   768
#define D_STATE   64
#define D_INNER   1536
#define HEADDIM   64
#define NHEADS    24
#define D_CONV    4
#define CONV_DIM  1664      // D_INNER + 2*D_STATE
#define D_IN_PROJ 3224      // 2*D_INNER + 2*D_STATE + NHEADS
#define BATCH     4
#define SEQLEN    2048
#define NROWS     (BATCH*SEQLEN)   // 8192
#define NSEG      8
#define SEGLEN    256              // SEQLEN / NSEG

typedef unsigned short u16;
typedef __attribute__((ext_vector_type(8))) short bf16x8;
typedef __attribute__((ext_vector_type(8))) unsigned short u16x8;
typedef __attribute__((ext_vector_type(4))) float f32x4;

__device__ __forceinline__ int flip_row(int m, const int* __restrict__ lengths) {
    int b = m >> 11;                 // SEQLEN = 2048
    int t = m & (SEQLEN - 1);
    int len = lengths[b];
    int ft = (t < len) ? (len - 1 - t) : t;
    return (b << 11) | ft;
}

__device__ __forceinline__ u16 f2bf(float f) {
    unsigned int u = __float_as_uint(f);
    unsigned int r = u + 0x7FFFu + ((u >> 16) & 1u);
    return (u16)(r >> 16);
}
__device__ __forceinline__ float bf2f(u16 h) {
    return __uint_as_float(((unsigned int)h) << 16);
}

// f32 -> (hi, lo) bf16 pair arrays
__global__ __launch_bounds__(256)
void convert_pair_kernel(const float* __restrict__ in, u16* __restrict__ hi,
                         u16* __restrict__ lo, int n4)
{
    int i = blockIdx.x * 256 + threadIdx.x;
    if (i >= n4) return;
    float4 v = *(const float4*)(in + (size_t)i * 4);
    ushort4 h, l;
    h.x = f2bf(v.x); l.x = f2bf(v.x - bf2f(h.x));
    h.y = f2bf(v.y); l.y = f2bf(v.y - bf2f(h.y));
    h.z = f2bf(v.z); l.z = f2bf(v.z - bf2f(h.z));
    h.w = f2bf(v.w); l.w = f2bf(v.w - bf2f(h.w));
    *(ushort4*)(hi + (size_t)i * 4) = h;
    *(ushort4*)(lo + (size_t)i * 4) = l;
}

// Split-bf16 MFMA GEMM: C[m, n] = sum_k (Ahi+Alo)[m,k] * (Whi+Wlo)[n,k]
// 128x128 tile, BK=64, 256 threads = 4 waves (2x2), 4x4 16x16 frags/wave.
// 3 MFMA terms: hi*hi + hi*lo + lo*hi.
// mode 0: C f32 = acc + bias[n] + resid[m]   (ldc)
// mode 1: split store -> Cz [.,1536] | Cxbc [.,1664] | Cdt [.,24]
// mode 2: bf16-pair store -> Cp rows of 3072 u16 ([hi 1536|lo 1536]), col ccol+n
__global__ __launch_bounds__(256, 2)
void mfma_gemm(const u16* __restrict__ Ahi, const u16* __restrict__ Alo, int lda,
               const u16* __restrict__ Whi, const u16* __restrict__ Wlo, int ldw,
               int N, int K, const int* __restrict__ lengths,
               int flipA, int flipC, int mode,
               float* __restrict__ C, int ldc,
               float* __restrict__ Cz, float* __restrict__ Cxbc,
               float* __restrict__ Cdt,
               u16* __restrict__ Cp, int ccol,
               const float* __restrict__ bias, const float* __restrict__ resid)
{
    __shared__ alignas(16) u16 lds[4 * 8192];   // regions: Ahi, Alo, Whi, Wlo
    const int tid = threadIdx.x;
    const int m0 = blockIdx.y * 128;
    const int n0 = blockIdx.x * 128;
    const int lane = tid & 63;
    const int wid = tid >> 6;
    const int wm = wid >> 1, wn = wid & 1;

    // ---- staging maps: thread covers (khalf = tid&7, rows rb+32c) ----
    const int kh = tid & 7;
    const int rb = tid >> 3;              // 0..31
    int aoff[4], woff[4], lws[4];
    #pragma unroll
    for (int c = 0; c < 4; c++) {
        int row = rb + c * 32;
        int grow = m0 + row;
        if (flipA) grow = flip_row(grow, lengths);
        aoff[c] = grow * lda + kh * 8;
        int wrow = n0 + row; if (wrow >= N) wrow = N - 1;
        woff[c] = wrow * ldw + kh * 8;
        // XOR-swizzled LDS offset (u16 units): conflict-free writes & reads
        lws[c] = kh * 1024 + ((row & 0x78) | ((row ^ kh) & 7)) * 8;
    }

    f32x4 acc[4][4];
    const f32x4 zero4 = {0.f, 0.f, 0.f, 0.f};
    #pragma unroll
    for (int i = 0; i < 4; i++)
        #pragma unroll
        for (int j = 0; j < 4; j++) acc[i][j] = zero4;

    const int l15 = lane & 15, lq = lane >> 4;
    const int arow0 = wm * 64 + l15;
    const int wrow0 = wn * 64 + l15;

    for (int kt = 0; kt < K; kt += 64) {
        u16x8 va[4], vb[4], vc[4], vd[4];
        #pragma unroll
        for (int c = 0; c < 4; c++) {
            va[c] = *(const u16x8*)(Ahi + (size_t)aoff[c] + kt);
            vb[c] = *(const u16x8*)(Alo + (size_t)aoff[c] + kt);
            vc[c] = *(const u16x8*)(Whi + (size_t)woff[c] + kt);
            vd[c] = *(const u16x8*)(Wlo + (size_t)woff[c] + kt);
        }
        __syncthreads();                       // previous tile's compute done
        #pragma unroll
        for (int c = 0; c < 4; c++) {
            *(u16x8*)(lds + 0 * 8192 + lws[c]) = va[c];
            *(u16x8*)(lds + 1 * 8192 + lws[c]) = vb[c];
            *(u16x8*)(lds + 2 * 8192 + lws[c]) = vc[c];
            *(u16x8*)(lds + 3 * 8192 + lws[c]) = vd[c];
        }
        __syncthreads();                       // tile staged
        #pragma unroll
        for (int kk = 0; kk < 2; kk++) {
            const int khs = kk * 4 + lq;
            const int abase = khs * 1024 + ((arow0 & 0x78) | ((arow0 ^ khs) & 7)) * 8;
            const int wbase = khs * 1024 + ((wrow0 & 0x78) | ((wrow0 ^ khs) & 7)) * 8;
            bf16x8 ah[4], al[4], wh[4], wl[4];
            #pragma unroll
            for (int f = 0; f < 4; f++) {
                ah[f] = *(const bf16x8*)(lds + 0 * 8192 + abase + f * 128);
                al[f] = *(const bf16x8*)(lds + 1 * 8192 + abase + f * 128);
                wh[f] = *(const bf16x8*)(lds + 2 * 8192 + wbase + f * 128);
                wl[f] = *(const bf16x8*)(lds + 3 * 8192 + wbase + f * 128);
            }
            #pragma unroll
            for (int fr = 0; fr < 4; fr++)
                #pragma unroll
                for (int fc = 0; fc < 4; fc++) {
                    acc[fr][fc] = __builtin_amdgcn_mfma_f32_16x16x32_bf16(
                        ah[fr], wh[fc], acc[fr][fc], 0, 0, 0);
                    acc[fr][fc] = __builtin_amdgcn_mfma_f32_16x16x32_bf16(
                        ah[fr], wl[fc], acc[fr][fc], 0, 0, 0);
                    acc[fr][fc] = __builtin_amdgcn_mfma_f32_16x16x32_bf16(
                        al[fr], wh[fc], acc[fr][fc], 0, 0, 0);
                }
        }
    }

    // ---- epilogue: D[row=(lq*4+reg)][col=l15] per 16x16 fragment ----
    #pragma unroll
    for (int fr = 0; fr < 4; fr++) {
        int mr[4], crow[4];
        #pragma unroll
        for (int r = 0; r < 4; r++) {
            mr[r] = m0 + wm * 64 + fr * 16 + lq * 4 + r;
            crow[r] = flipC ? flip_row(mr[r], lengths) : mr[r];
        }
        #pragma unroll
        for (int fc = 0; fc < 4; fc++) {
            const int nb = n0 + wn * 64 + fc * 16;   // fragment col base (uniform)
            const int nn = nb + l15;
            if (nn >= N) continue;
            #pragma unroll
            for (int r = 0; r < 4; r++) {
                float v = acc[fr][fc][r];
                if (mode == 1) {
                    if (nb < D_INNER)
                        Cz[(size_t)crow[r] * D_INNER + nn] = v;
                    else if (nb < D_INNER + CONV_DIM)
                        Cxbc[(size_t)crow[r] * CONV_DIM + (nn - D_INNER)] = v;
                    else
                        Cdt[(size_t)crow[r] * NHEADS + (nn - D_INNER - CONV_DIM)] = v;
                } else if (mode == 2) {
                    u16 h = f2bf(v);
                    u16 l = f2bf(v - bf2f(h));
                    size_t base = (size_t)crow[r] * 3072 + ccol + nn;
                    Cp[base] = h;
                    Cp[base + 1536] = l;
                } else {
                    v += bias[nn] + resid[(size_t)mr[r] * D_MODEL + nn];
                    C[(size_t)crow[r] * ldc + nn] = v;
                }
            }
        }
    }
}

// causal depthwise conv (width 4) + silu:  xbcr [row][CONV_DIM] -> xbc
__global__ __launch_bounds__(256)
void conv_silu_kernel(const float* __restrict__ xbcr, const float* __restrict__ cw,
                      const float* __restrict__ cb, float* __restrict__ xBC)
{
    const int c = blockIdx.x * 256 + threadIdx.x;
    const int row = blockIdx.y;
    if (c >= CONV_DIM) return;
    const int t = row & (SEQLEN - 1);
    float acc = cb[c];
    #pragma unroll
    for (int k = 0; k < D_CONV; k++) {
        int tt = t + k - (D_CONV - 1);
        if (tt >= 0)
            acc = fmaf(xbcr[(size_t)(row + k - (D_CONV-1)) * CONV_DIM + c],
                       cw[c * D_CONV + k], acc);
    }
    xBC[(size_t)row * CONV_DIM + c] = acc / (1.f + expf(-acc));
}

// dt = softplus(dt_raw + bias), dA = exp(dt * (-exp(A_log)))
__global__ __launch_bounds__(256)
void dt_kernel(const float* __restrict__ dtr, const float* __restrict__ dt_bias,
               const float* __restrict__ A_log, float* __restrict__ dt,
               float* __restrict__ dAe)
{
    int i = blockIdx.x * 256 + threadIdx.x;
    if (i >= NROWS * NHEADS) return;
    int h = i % NHEADS;
    float v = dtr[i] + dt_bias[h];
    float sp = (v > 20.f) ? v : log1pf(expf(v));
    float A = -expf(A_log[h]);
    dt[i] = sp;
    dAe[i] = expf(sp * A);
}

// Pass 1: segmented barrier-free scan. grid (96 bh, 8 seg, 16 pg), 64 thr.
__global__ __launch_bounds__(64)
void scan_seg_kernel(const float* __restrict__ xbc, const float* __restrict__ dtb,
                     const float* __restrict__ dab, const float* __restrict__ Dp,
                     float* __restrict__ y, float* __restrict__ hloc,
                     float* __restrict__ dcum)
{
    const int bh = blockIdx.x;
    const int b = bh / NHEADS, h = bh - b * NHEADS;
    const int s  = blockIdx.y;
    const int pg = blockIdx.z;
    const int lane = threadIdx.x;
    const int pl = lane >> 4, nq = lane & 15;
    const int p  = pg * 4 + pl;
    const int row0 = b * SEQLEN + s * SEGLEN;
    const float Dph = Dp[h];

    const float* xp = xbc + (size_t)row0 * CONV_DIM + h * HEADDIM + p;
    const float* Bp = xbc + (size_t)row0 * CONV_DIM + D_INNER + nq * 4;
    const float* Cp = Bp + D_STATE;
    const float* mp = dtb + (size_t)row0 * NHEADS + h;
    const float* ap = dab + (size_t)row0 * NHEADS + h;
    float* yp = y + (size_t)row0 * D_INNER + h * HEADDIM + p;
    float* dc = dcum + (size_t)row0 * NHEADS + h;

    float h0 = 0.f, h1 = 0.f, h2 = 0.f, h3 = 0.f, cumA = 1.f;

    float xv = *xp;
    float4 Bv = *(const float4*)Bp;
    float4 Cv = *(const float4*)Cp;
    float dtv = *mp, dav = *ap;

    for (int i = 0; i < SEGLEN; i++) {
        float xn = 0.f, dtn = 0.f, dan = 0.f;
        float4 Bn = make_float4(0,0,0,0), Cn = make_float4(0,0,0,0);
        if (i + 1 < SEGLEN) {
            xp += CONV_DIM; Bp += CONV_DIM; Cp += CONV_DIM; mp += NHEADS; ap += NHEADS;
            xn = *xp; Bn = *(const float4*)Bp; Cn = *(const float4*)Cp;
            dtn = *mp; dan = *ap;
        }
        const float dtx = dtv * xv;
        h0 = fmaf(h0, dav, dtx * Bv.x);
        h1 = fmaf(h1, dav, dtx * Bv.y);
        h2 = fmaf(h2, dav, dtx * Bv.z);
        h3 = fmaf(h3, dav, dtx * Bv.w);
        float acc = h0*Cv.x + h1*Cv.y + h2*Cv.z + h3*Cv.w;
        acc += __shfl_xor(acc, 1);
        acc += __shfl_xor(acc, 2);
        acc += __shfl_xor(acc, 4);
        acc += __shfl_xor(acc, 8);
        cumA *= dav;
        if (nq == 0) *yp = acc + Dph * xv;
        if (pg == 0 && lane == 0) *dc = cumA;
        yp += D_INNER; dc += NHEADS;
        xv = xn; Bv = Bn; Cv = Cn; dtv = dtn; dav = dan;
    }
    *(float4*)(hloc + ((size_t)(bh * NSEG + s)) * 4096 + p * 64 + nq * 4) =
        make_float4(h0, h1, h2, h3);
}

// Pass 2: sequential fold of segment states.
__global__ __launch_bounds__(256)
void combine_kernel(const float* __restrict__ hloc, const float* __restrict__ dcum,
                    float* __restrict__ hin)
{
    const int bh = blockIdx.x;
    const int b = bh / NHEADS, h = bh - b * NHEADS;
    const int tid = threadIdx.x;
    float4 hv[4];
    #pragma unroll
    for (int j = 0; j < 4; j++) hv[j] = make_float4(0,0,0,0);
    for (int s = 0; s < NSEG; s++) {
        float* out = hin + (size_t)(bh * NSEG + s) * 4096 + tid * 16;
        #pragma unroll
        for (int j = 0; j < 4; j++) *(float4*)(out + j*4) = hv[j];
        if (s < NSEG - 1) {
            float P = dcum[((size_t)(b * SEQLEN + s * SEGLEN + SEGLEN - 1)) * NHEADS + h];
            const float* hl = hloc + (size_t)(bh * NSEG + s) * 4096 + tid * 16;
            #pragma unroll
            for (int j = 0; j < 4; j++) {
                float4 lv = *(const float4*)(hl + j*4);
                hv[j].x = fmaf(hv[j].x, P, lv.x);
                hv[j].y = fmaf(hv[j].y, P, lv.y);
                hv[j].z = fmaf(hv[j].z, P, lv.z);
                hv[j].w = fmaf(hv[j].w, P, lv.w);
            }
        }
    }
}

// Pass 3: y[t] += dcum[t] * (C[t] . h_in[seg(t)])
__global__ __launch_bounds__(256)
void corr_kernel(const float* __restrict__ xbc, const float* __restrict__ dcum,
                 const float* __restrict__ hin, float* __restrict__ y)
{
    const int bh = blockIdx.x;
    const int b = bh / NHEADS, h = bh - b * NHEADS;
    const int s = blockIdx.y + 1;
    const int tid = threadIdx.x;
    const int rg = tid >> 6;
    const int p  = tid & 63;

    const float* hp = hin + (size_t)(bh * NSEG + s) * 4096 + p * 64;
    float4 H[16];
    #pragma unroll
    for (int j = 0; j < 16; j++) H[j] = *(const float4*)(hp + j * 4);

    const int row0 = b * SEQLEN + s * SEGLEN;
    for (int i = rg; i < SEGLEN; i += 4) {
        const size_t row = row0 + i;
        const float* Crow = xbc + row * CONV_DIM + D_INNER + D_STATE;
        const float cA = dcum[row * NHEADS + h];
        float acc = 0.f;
        #pragma unroll
        for (int j = 0; j < 16; j++) {
            float4 c = *(const float4*)(Crow + j * 4);
            acc += H[j].x*c.x + H[j].y*c.y + H[j].z*c.z + H[j].w*c.w;
        }
        y[row * D_INNER + h * HEADDIM + p] += cA * acc;
    }
}

// gate with silu(z) + RMSNorm, then IN-PLACE per-row bf16 pair split:
// row bytes become [hi u16 x1536 | lo u16 x1536] (same footprint as f32 row)
__global__ __launch_bounds__(256)
void gate_rmsnorm_pair_kernel(float* __restrict__ y, const float* __restrict__ z,
                              const float* __restrict__ norm_w)
{
    const int row = blockIdx.x;
    const float* zr = z + (size_t)row * D_INNER;
    float* yr = y + (size_t)row * D_INNER;
    const int tid = threadIdx.x;
    float g[6];
    float ss = 0.f;
    #pragma unroll
    for (int i = 0; i < 6; i++) {
        int e = tid + i * 256;
        float zv = zr[e];
        float gv = yr[e] * (zv / (1.f + expf(-zv)));
        g[i] = gv;
        ss = fmaf(gv, gv, ss);
    }
    #pragma unroll
    for (int o = 32; o > 0; o >>= 1) ss += __shfl_xor(ss, o);
    __shared__ float red[4];
    if ((tid & 63) == 0) red[tid >> 6] = ss;
    __syncthreads();   // also guarantees all row reads complete before writes
    float tot = red[0] + red[1] + red[2] + red[3];
    float scale = rsqrtf(tot * (1.f / D_INNER) + 1e-5f);
    u16* out = (u16*)yr;
    #pragma unroll
    for (int i = 0; i < 6; i++) {
        int e = tid + i * 256;
        float gv = g[i] * scale * norm_w[e];
        u16 h = f2bf(gv);
        out[e] = h;
        out[D_INNER + e] = f2bf(gv - bf2f(h));
    }
}

__global__ __launch_bounds__(256)
void layernorm_kernel(const float* __restrict__ r, const float* __restrict__ gam,
                      const float* __restrict__ bet, float* __restrict__ out)
{
    const int row = blockIdx.x;
    const float* rr = r + (size_t)row * D_MODEL;
    const int tid = threadIdx.x;
    float v[3];
    float s = 0.f, s2 = 0.f;
    #pragma unroll
    for (int i = 0; i < 3; i++) {
        v[i] = rr[tid + i * 256];
        s += v[i];
        s2 = fmaf(v[i], v[i], s2);
    }
    #pragma unroll
    for (int o = 32; o > 0; o >>= 1) { s += __shfl_xor(s, o); s2 += __shfl_xor(s2, o); }
    __shared__ float rs[4], rs2[4];
    if ((tid & 63) == 0) { rs[tid >> 6] = s; rs2[tid >> 6] = s2; }
    __syncthreads();
    float S  = rs[0] + rs[1] + rs[2] + rs[3];
    float S2 = rs2[0] + rs2[1] + rs2[2] + rs2[3];
    float mu  = S * (1.f / D_MODEL);
    float var = S2 * (1.f / D_MODEL) - mu * mu;
    float inv = rsqrtf(var + 1e-5f);
    #pragma unroll
    for (int i = 0; i < 3; i++) {
        int e = tid + i * 256;
        out[(size_t)row * D_MODEL + e] = (v[i] - mu) * inv * gam[e] + bet[e];
    }
}

extern "C" void kernel_launch(void* const* d_in, const int* in_sizes, int n_in,
                              void* d_out, int out_size, void* d_ws, size_t ws_size,
                              hipStream_t stream)
{
    const float* x        = (const float*)d_in[0];
    const int*   lengths  = (const int*)d_in[1];
    const float* in_w[2]    = {(const float*)d_in[2],  (const float*)d_in[10]};
    const float* conv_w[2]  = {(const float*)d_in[3],  (const float*)d_in[11]};
    const float* conv_b[2]  = {(const float*)d_in[4],  (const float*)d_in[12]};
    const float* dt_bias[2] = {(const float*)d_in[5],  (const float*)d_in[13]};
    const float* A_log[2]   = {(const float*)d_in[6],  (const float*)d_in[14]};
    const float* Dp[2]      = {(const float*)d_in[7],  (const float*)d_in[15]};
    const float* norm_w[2]  = {(const float*)d_in[8],  (const float*)d_in[16]};
    const float* out_w[2]   = {(const float*)d_in[9],  (const float*)d_in[17]};
    const float* op_w = (const float*)d_in[18];
    const float* op_b = (const float*)d_in[19];
    const float* ln_g = (const float*)d_in[20];
    const float* ln_b = (const float*)d_in[21];
    float* outp = (float*)d_out;

    // workspace layout (262.4 MB, unchanged footprint)
    float* z    = (float*)d_ws;                               // 8192*1536
    float* xbcr = z    + (size_t)NROWS * D_INNER;             // 8192*1664
    float* dtr  = xbcr + (size_t)NROWS * CONV_DIM;            // 8192*24
    float* dtb  = dtr  + (size_t)NROWS * NHEADS;              // 8192*24
    float* dab  = dtb  + (size_t)NROWS * NHEADS;              // 8192*24
    float* xbc  = dab  + (size_t)NROWS * NHEADS;              // 8192*1664
    float* ybuf = xbc  + (size_t)NROWS * CONV_DIM;            // 8192*1536
    float* comb = ybuf + (size_t)NROWS * D_INNER;             // 8192*1536
    // scan scratch reuses xbcr region (dead between conv and next dir's GEMM)
    float* hloc = xbcr;
    float* hin  = hloc + (size_t)BATCH*NHEADS*NSEG*4096;
    float* dcum = hin  + (size_t)BATCH*NHEADS*NSEG*4096;
    float* rbuf = z;   // final residual buffer reuses z

    // bf16 conversion staging inside the (temporally dead) xbc region:
    u16* xq_h = (u16*)xbc;
    u16* xq_l = xq_h + (size_t)NROWS * D_MODEL;
    u16* iw_h = xq_l + (size_t)NROWS * D_MODEL;
    u16* iw_l = iw_h + (size_t)D_IN_PROJ * D_MODEL;
    u16* ow_h = (u16*)xbc;                       // after corr, per dir
    u16* ow_l = ow_h + (size_t)D_MODEL * D_INNER;
    u16* op_h = (u16*)xbc;                       // after both dirs
    u16* op_l = op_h + (size_t)D_MODEL * D_INNER;
    // gated y as in-place bf16 pairs in ybuf; comb as bf16 pairs in comb region
    u16* yg_p   = (u16*)ybuf;   // rows of 3072 u16: [hi|lo]
    u16* comb_p = (u16*)comb;   // rows of 3072 u16: [hi|lo], cols: fwd 0-767, bwd 768-1535

    size_t need = ((size_t)NROWS * (D_INNER + CONV_DIM + 3*NHEADS + CONV_DIM +
                                    D_INNER + D_INNER)) * sizeof(float);
    if (ws_size < need) return;

    for (int dir = 0; dir < 2; dir++) {
        // 0. convert x and in_w to bf16 hi/lo (xbc region)
        convert_pair_kernel<<<(NROWS*D_MODEL/4 + 255)/256, 256, 0, stream>>>(
            x, xq_h, xq_l, NROWS*D_MODEL/4);
        convert_pair_kernel<<<(D_IN_PROJ*D_MODEL/4 + 255)/256, 256, 0, stream>>>(
            in_w[dir], iw_h, iw_l, D_IN_PROJ*D_MODEL/4);
        // 1. in_proj MFMA GEMM (split outputs): [z | xbcr | dtr]
        mfma_gemm<<<dim3(26, 64), 256, 0, stream>>>(
            xq_h, xq_l, D_MODEL, iw_h, iw_l, D_MODEL, D_IN_PROJ, D_MODEL,
            lengths, dir, 0, 1,
            nullptr, 0, z, xbcr, dtr, nullptr, 0, nullptr, nullptr);
        // 2. causal conv + silu -> xbc (overwrites conversion buffers)
        conv_silu_kernel<<<dim3(7, NROWS), 256, 0, stream>>>(xbcr, conv_w[dir], conv_b[dir], xbc);
        // 3. dt / dA precompute
        dt_kernel<<<(NROWS*NHEADS + 255)/256, 256, 0, stream>>>(dtr, dt_bias[dir], A_log[dir], dtb, dab);
        // 4. segmented scan (scratch in xbcr region)
        scan_seg_kernel<<<dim3(BATCH*NHEADS, NSEG, 16), 64, 0, stream>>>(
            xbc, dtb, dab, Dp[dir], ybuf, hloc, dcum);
        combine_kernel<<<BATCH*NHEADS, 256, 0, stream>>>(hloc, dcum, hin);
        corr_kernel<<<dim3(BATCH*NHEADS, NSEG-1), 256, 0, stream>>>(xbc, dcum, hin, ybuf);
        // 5. gate + RMSNorm -> in-place bf16 pairs
        gate_rmsnorm_pair_kernel<<<NROWS, 256, 0, stream>>>(ybuf, z, norm_w[dir]);
        // 6. convert out_w (xbc region, now dead) and run out_proj -> comb pairs
        convert_pair_kernel<<<(D_MODEL*D_INNER/4 + 255)/256, 256, 0, stream>>>(
            out_w[dir], ow_h, ow_l, D_MODEL*D_INNER/4);
        mfma_gemm<<<dim3(6, 64), 256, 0, stream>>>(
            yg_p, yg_p + D_INNER, 3072, ow_h, ow_l, D_INNER, D_MODEL, D_INNER,
            lengths, 0, dir, 2,
            nullptr, 0, nullptr, nullptr, nullptr, comb_p, dir * D_MODEL,
            nullptr, nullptr);
    }

    // final: rbuf = comb @ op_w^T + op_b + x
    convert_pair_kernel<<<(D_MODEL*D_INNER/4 + 255)/256, 256, 0, stream>>>(
        op_w, op_h, op_l, D_MODEL*D_INNER/4);
    mfma_gemm<<<dim3(6, 64), 256, 0, stream>>>(
        comb_p, comb_p + 1536, 3072, op_h, op_l, 2*D_MODEL, D_MODEL, 2*D_MODEL,
        lengths, 0, 0, 0,
        rbuf, D_MODEL, nullptr, nullptr, nullptr, nullptr, 0, op_b, x);
    // layernorm -> out
    layernorm_kernel<<<NROWS, 256, 0, stream>>>(rbuf, ln_g, ln_b, outp);
}

// Round 6
// 997.316 us; speedup vs baseline: 5.7765x; 1.6435x over previous
//
#include <hip/hip_runtime.h>
#include <cstdint>
#include <cstddef>

#define D_MODEL   768
#define D_STATE   64
#define D_INNER   1536
#define HEADDIM   64
#define NHEADS    24
#define D_CONV    4
#define CONV_DIM  1664      // D_INNER + 2*D_STATE
#define D_IN_PROJ 3224      // 2*D_INNER + 2*D_STATE + NHEADS
#define BATCH     4
#define SEQLEN    2048
#define NROWS     (BATCH*SEQLEN)   // 8192
#define NCHUNK    32
#define Q         64               // chunk length

typedef unsigned short u16;
typedef __attribute__((ext_vector_type(8))) short bf16x8;
typedef __attribute__((ext_vector_type(8))) unsigned short u16x8;
typedef __attribute__((ext_vector_type(4))) float f32x4;

__device__ __forceinline__ int flip_row(int m, const int* __restrict__ lengths) {
    int b = m >> 11;
    int t = m & (SEQLEN - 1);
    int len = lengths[b];
    int ft = (t < len) ? (len - 1 - t) : t;
    return (b << 11) | ft;
}

__device__ __forceinline__ u16 f2bf(float f) {
    unsigned int u = __float_as_uint(f);
    unsigned int r = u + 0x7FFFu + ((u >> 16) & 1u);
    return (u16)(r >> 16);
}
__device__ __forceinline__ float bf2f(u16 h) {
    return __uint_as_float(((unsigned int)h) << 16);
}

// f32 -> (hi, lo) bf16 pair arrays
__global__ __launch_bounds__(256)
void convert_pair_kernel(const float* __restrict__ in, u16* __restrict__ hi,
                         u16* __restrict__ lo, int n4)
{
    int i = blockIdx.x * 256 + threadIdx.x;
    if (i >= n4) return;
    float4 v = *(const float4*)(in + (size_t)i * 4);
    ushort4 h, l;
    h.x = f2bf(v.x); l.x = f2bf(v.x - bf2f(h.x));
    h.y = f2bf(v.y); l.y = f2bf(v.y - bf2f(h.y));
    h.z = f2bf(v.z); l.z = f2bf(v.z - bf2f(h.z));
    h.w = f2bf(v.w); l.w = f2bf(v.w - bf2f(h.w));
    *(ushort4*)(hi + (size_t)i * 4) = h;
    *(ushort4*)(lo + (size_t)i * 4) = l;
}

// ---------- big split-bf16 MFMA GEMM (unchanged from R5) ----------
__global__ __launch_bounds__(256, 2)
void mfma_gemm(const u16* __restrict__ Ahi, const u16* __restrict__ Alo, int lda,
               const u16* __restrict__ Whi, const u16* __restrict__ Wlo, int ldw,
               int N, int K, const int* __restrict__ lengths,
               int flipA, int flipC, int mode,
               float* __restrict__ C, int ldc,
               float* __restrict__ Cz, float* __restrict__ Cxbc,
               float* __restrict__ Cdt,
               u16* __restrict__ Cp, int ccol,
               const float* __restrict__ bias, const float* __restrict__ resid)
{
    __shared__ alignas(16) u16 lds[4 * 8192];
    const int tid = threadIdx.x;
    const int m0 = blockIdx.y * 128;
    const int n0 = blockIdx.x * 128;
    const int lane = tid & 63;
    const int wid = tid >> 6;
    const int wm = wid >> 1, wn = wid & 1;

    const int kh = tid & 7;
    const int rb = tid >> 3;
    int aoff[4], woff[4], lws[4];
    #pragma unroll
    for (int c = 0; c < 4; c++) {
        int row = rb + c * 32;
        int grow = m0 + row;
        if (flipA) grow = flip_row(grow, lengths);
        aoff[c] = grow * lda + kh * 8;
        int wrow = n0 + row; if (wrow >= N) wrow = N - 1;
        woff[c] = wrow * ldw + kh * 8;
        lws[c] = kh * 1024 + ((row & 0x78) | ((row ^ kh) & 7)) * 8;
    }

    f32x4 acc[4][4];
    const f32x4 zero4 = {0.f, 0.f, 0.f, 0.f};
    #pragma unroll
    for (int i = 0; i < 4; i++)
        #pragma unroll
        for (int j = 0; j < 4; j++) acc[i][j] = zero4;

    const int l15 = lane & 15, lq = lane >> 4;
    const int arow0 = wm * 64 + l15;
    const int wrow0 = wn * 64 + l15;

    for (int kt = 0; kt < K; kt += 64) {
        u16x8 va[4], vb[4], vc[4], vd[4];
        #pragma unroll
        for (int c = 0; c < 4; c++) {
            va[c] = *(const u16x8*)(Ahi + (size_t)aoff[c] + kt);
            vb[c] = *(const u16x8*)(Alo + (size_t)aoff[c] + kt);
            vc[c] = *(const u16x8*)(Whi + (size_t)woff[c] + kt);
            vd[c] = *(const u16x8*)(Wlo + (size_t)woff[c] + kt);
        }
        __syncthreads();
        #pragma unroll
        for (int c = 0; c < 4; c++) {
            *(u16x8*)(lds + 0 * 8192 + lws[c]) = va[c];
            *(u16x8*)(lds + 1 * 8192 + lws[c]) = vb[c];
            *(u16x8*)(lds + 2 * 8192 + lws[c]) = vc[c];
            *(u16x8*)(lds + 3 * 8192 + lws[c]) = vd[c];
        }
        __syncthreads();
        #pragma unroll
        for (int kk = 0; kk < 2; kk++) {
            const int khs = kk * 4 + lq;
            const int abase = khs * 1024 + ((arow0 & 0x78) | ((arow0 ^ khs) & 7)) * 8;
            const int wbase = khs * 1024 + ((wrow0 & 0x78) | ((wrow0 ^ khs) & 7)) * 8;
            bf16x8 ah[4], al[4], wh[4], wl[4];
            #pragma unroll
            for (int f = 0; f < 4; f++) {
                ah[f] = *(const bf16x8*)(lds + 0 * 8192 + abase + f * 128);
                al[f] = *(const bf16x8*)(lds + 1 * 8192 + abase + f * 128);
                wh[f] = *(const bf16x8*)(lds + 2 * 8192 + wbase + f * 128);
                wl[f] = *(const bf16x8*)(lds + 3 * 8192 + wbase + f * 128);
            }
            #pragma unroll
            for (int fr = 0; fr < 4; fr++)
                #pragma unroll
                for (int fc = 0; fc < 4; fc++) {
                    acc[fr][fc] = __builtin_amdgcn_mfma_f32_16x16x32_bf16(
                        ah[fr], wh[fc], acc[fr][fc], 0, 0, 0);
                    acc[fr][fc] = __builtin_amdgcn_mfma_f32_16x16x32_bf16(
                        ah[fr], wl[fc], acc[fr][fc], 0, 0, 0);
                    acc[fr][fc] = __builtin_amdgcn_mfma_f32_16x16x32_bf16(
                        al[fr], wh[fc], acc[fr][fc], 0, 0, 0);
                }
        }
    }

    #pragma unroll
    for (int fr = 0; fr < 4; fr++) {
        int mr[4], crow[4];
        #pragma unroll
        for (int r = 0; r < 4; r++) {
            mr[r] = m0 + wm * 64 + fr * 16 + lq * 4 + r;
            crow[r] = flipC ? flip_row(mr[r], lengths) : mr[r];
        }
        #pragma unroll
        for (int fc = 0; fc < 4; fc++) {
            const int nb = n0 + wn * 64 + fc * 16;
            const int nn = nb + l15;
            if (nn >= N) continue;
            #pragma unroll
            for (int r = 0; r < 4; r++) {
                float v = acc[fr][fc][r];
                if (mode == 1) {
                    if (nb < D_INNER)
                        Cz[(size_t)crow[r] * D_INNER + nn] = v;
                    else if (nb < D_INNER + CONV_DIM)
                        Cxbc[(size_t)crow[r] * CONV_DIM + (nn - D_INNER)] = v;
                    else
                        Cdt[(size_t)crow[r] * NHEADS + (nn - D_INNER - CONV_DIM)] = v;
                } else if (mode == 2) {
                    u16 h = f2bf(v);
                    u16 l = f2bf(v - bf2f(h));
                    size_t base = (size_t)crow[r] * 3072 + ccol + nn;
                    Cp[base] = h;
                    Cp[base + 1536] = l;
                } else {
                    v += bias[nn] + resid[(size_t)mr[r] * D_MODEL + nn];
                    C[(size_t)crow[r] * ldc + nn] = v;
                }
            }
        }
    }
}

// causal conv + silu; x part -> f32 xconv[8192][1536], B/C part -> bf16 pairs [8192][128]
__global__ __launch_bounds__(256)
void conv_silu_split_kernel(const float* __restrict__ xbcr, const float* __restrict__ cw,
                            const float* __restrict__ cb, float* __restrict__ xconv,
                            u16* __restrict__ bch, u16* __restrict__ bcl)
{
    const int c = blockIdx.x * 256 + threadIdx.x;
    const int row = blockIdx.y;
    if (c >= CONV_DIM) return;
    const int t = row & (SEQLEN - 1);
    float acc = cb[c];
    #pragma unroll
    for (int k = 0; k < D_CONV; k++) {
        int tt = t + k - (D_CONV - 1);
        if (tt >= 0)
            acc = fmaf(xbcr[(size_t)(row + k - (D_CONV-1)) * CONV_DIM + c],
                       cw[c * D_CONV + k], acc);
    }
    float val = acc / (1.f + expf(-acc));
    if (c < D_INNER) {
        xconv[(size_t)row * D_INNER + c] = val;
    } else {
        u16 h = f2bf(val);
        bch[(size_t)row * 128 + (c - D_INNER)] = h;
        bcl[(size_t)row * 128 + (c - D_INNER)] = f2bf(val - bf2f(h));
    }
}

// dt = softplus(dt_raw + bias); dtA = dt * (-exp(A_log))
__global__ __launch_bounds__(256)
void dt_kernel(const float* __restrict__ dtr, const float* __restrict__ dt_bias,
               const float* __restrict__ A_log, float* __restrict__ dtb,
               float* __restrict__ dtA)
{
    int i = blockIdx.x * 256 + threadIdx.x;
    if (i >= NROWS * NHEADS) return;
    int h = i % NHEADS;
    float v = dtr[i] + dt_bias[h];
    float sp = (v > 20.f) ? v : log1pf(expf(v));
    float A = -expf(A_log[h]);
    dtb[i] = sp;
    dtA[i] = sp * A;
}

// per-chunk inclusive cumsum of dtA -> la   (grid (96 bh, 32 c), 64 threads)
__global__ __launch_bounds__(64)
void cumsum_kernel(const float* __restrict__ dtA, float* __restrict__ la)
{
    int bh = blockIdx.x, c = blockIdx.y;
    int b = bh / NHEADS, h = bh - b * NHEADS;
    int row = b * SEQLEN + c * Q + threadIdx.x;
    float v = dtA[(size_t)row * NHEADS + h];
    #pragma unroll
    for (int o = 1; o < 64; o <<= 1) {
        float u = __shfl_up(v, o);
        if ((int)threadIdx.x >= o) v += u;
    }
    la[(size_t)row * NHEADS + h] = v;
}

// xconv -> per-(bh,chunk) transposed bf16-pair tiles xT[tile][p][s]
__global__ __launch_bounds__(256)
void transpose_pair_kernel(const float* __restrict__ xconv,
                           u16* __restrict__ xTh, u16* __restrict__ xTl)
{
    __shared__ float T[64][65];
    const int h = blockIdx.x;          // 0..23
    const int rc = blockIdx.y;         // 0..127 : b = rc>>5, chunk = rc&31
    const int row0 = rc * 64;
    const int tid = threadIdx.x;
    const int col = tid & 63, rg = tid >> 6;
    #pragma unroll
    for (int i = 0; i < 16; i++) {
        int r = i * 4 + rg;
        T[r][col] = xconv[(size_t)(row0 + r) * D_INNER + h * 64 + col];
    }
    __syncthreads();
    const int p = tid >> 2, s0 = (tid & 3) * 16;
    size_t tile = (size_t)(((rc >> 5) * NHEADS + h) * NCHUNK + (rc & 31));
    size_t base = tile * 4096 + p * 64 + s0;
    u16x8 ph[2], pl[2];
    #pragma unroll
    for (int j = 0; j < 16; j++) {
        float v = T[s0 + j][p];
        u16 hh = f2bf(v);
        ph[j >> 3][j & 7] = hh;
        pl[j >> 3][j & 7] = f2bf(v - bf2f(hh));
    }
    *(u16x8*)(xTh + base)     = ph[0];
    *(u16x8*)(xTh + base + 8) = ph[1];
    *(u16x8*)(xTl + base)     = pl[0];
    *(u16x8*)(xTl + base + 8) = pl[1];
}

// 3-term split-bf16 64x64x64 GEMM helper on staged LDS regions
__device__ __forceinline__ void gemm3(const u16* rA, const u16* rW,
                                      int ar0, int wr0, int lq, f32x4 acc[2][2])
{
    #pragma unroll
    for (int kk = 0; kk < 2; kk++) {
        const int khs = kk * 4 + lq;
        const int ab = khs * 512 + ((ar0 & 0x38) | ((ar0 ^ khs) & 7)) * 8;
        const int wb = khs * 512 + ((wr0 & 0x38) | ((wr0 ^ khs) & 7)) * 8;
        bf16x8 ah[2], al[2], wh[2], wl[2];
        #pragma unroll
        for (int f = 0; f < 2; f++) {
            ah[f] = *(const bf16x8*)(rA + ab + f * 128);
            al[f] = *(const bf16x8*)(rA + 4096 + ab + f * 128);
            wh[f] = *(const bf16x8*)(rW + wb + f * 128);
            wl[f] = *(const bf16x8*)(rW + 4096 + wb + f * 128);
        }
        #pragma unroll
        for (int fr = 0; fr < 2; fr++)
            #pragma unroll
            for (int fc = 0; fc < 2; fc++) {
                acc[fr][fc] = __builtin_amdgcn_mfma_f32_16x16x32_bf16(ah[fr], wh[fc], acc[fr][fc], 0, 0, 0);
                acc[fr][fc] = __builtin_amdgcn_mfma_f32_16x16x32_bf16(ah[fr], wl[fc], acc[fr][fc], 0, 0, 0);
                acc[fr][fc] = __builtin_amdgcn_mfma_f32_16x16x32_bf16(al[fr], wh[fc], acc[fr][fc], 0, 0, 0);
            }
    }
}

// chunk state: S(p,n) = sum_s exp(la63-la[s]) dt[s] x[s][p] B[s][n]  -> hloc[tile]
__global__ __launch_bounds__(256)
void chunk_state_kernel(const u16* __restrict__ xTh, const u16* __restrict__ xTl,
                        const u16* __restrict__ bch, const u16* __restrict__ bcl,
                        const float* __restrict__ la, const float* __restrict__ dtb,
                        float* __restrict__ hloc)
{
    __shared__ alignas(16) u16 lA[2 * 4096];
    __shared__ alignas(16) u16 lW[2 * 4096];
    __shared__ float la_sh[64], w_sh[64];
    const int bh = blockIdx.x, c = blockIdx.y;
    const int b = bh / NHEADS, h = bh - b * NHEADS;
    const int row0 = b * SEQLEN + c * Q;
    const size_t tile = (size_t)(bh * NCHUNK + c);
    const int tid = threadIdx.x;

    if (tid < 64) la_sh[tid] = la[(size_t)(row0 + tid) * NHEADS + h];
    __syncthreads();
    if (tid < 64)
        w_sh[tid] = expf(la_sh[63] - la_sh[tid]) * dtb[(size_t)(row0 + tid) * NHEADS + h];
    // stage A = Xt pairs
    {
        const int kh = tid & 7, rr = tid >> 3;
        #pragma unroll
        for (int cc = 0; cc < 2; cc++) {
            int row = rr + cc * 32;
            int lws = kh * 512 + ((row & 0x38) | ((row ^ kh) & 7)) * 8;
            *(u16x8*)(lA + lws)        = *(const u16x8*)(xTh + tile * 4096 + row * 64 + kh * 8);
            *(u16x8*)(lA + 4096 + lws) = *(const u16x8*)(xTl + tile * 4096 + row * 64 + kh * 8);
        }
    }
    __syncthreads();
    // stage W = (w*B)^T pairs (transposed scatter)
    {
        const int n = tid & 63, sg = tid >> 6;
        #pragma unroll
        for (int i = 0; i < 16; i++) {
            int s = sg + i * 4;
            size_t gidx = (size_t)(row0 + s) * 128 + n;
            float bv = bf2f(bch[gidx]) + bf2f(bcl[gidx]);
            float v = bv * w_sh[s];
            u16 hh = f2bf(v), ll = f2bf(v - bf2f(hh));
            int addr = (s >> 3) * 512 + ((n & 0x38) | ((n ^ (s >> 3)) & 7)) * 8 + (s & 7);
            lW[addr] = hh;
            lW[4096 + addr] = ll;
        }
    }
    __syncthreads();
    const int lane = tid & 63, wid = tid >> 6;
    const int wm = wid >> 1, wn = wid & 1;
    const int l15 = lane & 15, lq = lane >> 4;
    f32x4 acc[2][2];
    const f32x4 z4 = {0.f, 0.f, 0.f, 0.f};
    acc[0][0] = z4; acc[0][1] = z4; acc[1][0] = z4; acc[1][1] = z4;
    gemm3(lA, lW, wm * 32 + l15, wn * 32 + l15, lq, acc);
    #pragma unroll
    for (int fr = 0; fr < 2; fr++)
        #pragma unroll
        for (int fc = 0; fc < 2; fc++)
            #pragma unroll
            for (int r = 0; r < 4; r++) {
                int p = wm * 32 + fr * 16 + lq * 4 + r;
                int n = wn * 32 + fc * 16 + l15;
                hloc[tile * 4096 + p * 64 + n] = acc[fr][fc][r];
            }
}

// in-place sequential fold: hloc[c] := state ENTERING chunk c
__global__ __launch_bounds__(256)
void combine_kernel(float* __restrict__ hloc, const float* __restrict__ la)
{
    const int bh = blockIdx.x;
    const int b = bh / NHEADS, h = bh - b * NHEADS;
    const int tid = threadIdx.x;
    float4 run[4];
    #pragma unroll
    for (int j = 0; j < 4; j++) run[j] = make_float4(0.f, 0.f, 0.f, 0.f);
    for (int c = 0; c < NCHUNK; c++) {
        float* ptr = hloc + ((size_t)(bh * NCHUNK + c)) * 4096 + tid * 16;
        float4 sv[4];
        #pragma unroll
        for (int j = 0; j < 4; j++) sv[j] = *(const float4*)(ptr + j * 4);
        #pragma unroll
        for (int j = 0; j < 4; j++) *(float4*)(ptr + j * 4) = run[j];
        float cd = expf(la[(size_t)(b * SEQLEN + c * Q + Q - 1) * NHEADS + h]);
        #pragma unroll
        for (int j = 0; j < 4; j++) {
            run[j].x = fmaf(run[j].x, cd, sv[j].x);
            run[j].y = fmaf(run[j].y, cd, sv[j].y);
            run[j].z = fmaf(run[j].z, cd, sv[j].z);
            run[j].w = fmaf(run[j].w, cd, sv[j].w);
        }
    }
}

// chunk y: y[t][p] = sum_s P[t][s] x[s][p] + exp(la[t]) * (C[t] . hin[p])
//          with P[t][s] = (C[t].B[s]) exp(la[t]-la[s]) dt[s]  (s<=t),  P[t][t] += D
__global__ __launch_bounds__(256)
void chunk_y_kernel(const u16* __restrict__ xTh, const u16* __restrict__ xTl,
                    const u16* __restrict__ bch, const u16* __restrict__ bcl,
                    const float* __restrict__ hloc, const float* __restrict__ la,
                    const float* __restrict__ dtb, const float* __restrict__ Dp,
                    float* __restrict__ y)
{
    __shared__ alignas(16) u16 r1[2 * 4096];   // C pairs -> P pairs
    __shared__ alignas(16) u16 r2[2 * 4096];   // hin -> B -> X pairs
    __shared__ float la_sh[64], dt_sh[64];
    const int bh = blockIdx.x, c = blockIdx.y;
    const int b = bh / NHEADS, h = bh - b * NHEADS;
    const int row0 = b * SEQLEN + c * Q;
    const size_t tile = (size_t)(bh * NCHUNK + c);
    const int tid = threadIdx.x;
    if (tid < 64) {
        la_sh[tid] = la[(size_t)(row0 + tid) * NHEADS + h];
        dt_sh[tid] = dtb[(size_t)(row0 + tid) * NHEADS + h];
    }
    const int kh = tid & 7, rr = tid >> 3;
    // stage C (rows t, k=n) into r1 ; hin (rows p, k=n) into r2
    #pragma unroll
    for (int cc = 0; cc < 2; cc++) {
        int row = rr + cc * 32;
        int lws = kh * 512 + ((row & 0x38) | ((row ^ kh) & 7)) * 8;
        *(u16x8*)(r1 + lws)        = *(const u16x8*)(bch + (size_t)(row0 + row) * 128 + 64 + kh * 8);
        *(u16x8*)(r1 + 4096 + lws) = *(const u16x8*)(bcl + (size_t)(row0 + row) * 128 + 64 + kh * 8);
        float4 f0 = *(const float4*)(hloc + tile * 4096 + row * 64 + kh * 8);
        float4 f1 = *(const float4*)(hloc + tile * 4096 + row * 64 + kh * 8 + 4);
        float vals[8] = {f0.x, f0.y, f0.z, f0.w, f1.x, f1.y, f1.z, f1.w};
        u16x8 hh, ll;
        #pragma unroll
        for (int j = 0; j < 8; j++) {
            u16 a = f2bf(vals[j]);
            hh[j] = a;
            ll[j] = f2bf(vals[j] - bf2f(a));
        }
        *(u16x8*)(r2 + lws) = hh;
        *(u16x8*)(r2 + 4096 + lws) = ll;
    }
    __syncthreads();
    const int lane = tid & 63, wid = tid >> 6;
    const int wm = wid >> 1, wn = wid & 1;
    const int l15 = lane & 15, lq = lane >> 4;
    const int ar0 = wm * 32 + l15, wr0 = wn * 32 + l15;
    const f32x4 z4 = {0.f, 0.f, 0.f, 0.f};
    // Y2 = C @ hin^T
    f32x4 acc2[2][2];
    acc2[0][0] = z4; acc2[0][1] = z4; acc2[1][0] = z4; acc2[1][1] = z4;
    gemm3(r1, r2, ar0, wr0, lq, acc2);
    __syncthreads();
    // stage B into r2
    #pragma unroll
    for (int cc = 0; cc < 2; cc++) {
        int row = rr + cc * 32;
        int lws = kh * 512 + ((row & 0x38) | ((row ^ kh) & 7)) * 8;
        *(u16x8*)(r2 + lws)        = *(const u16x8*)(bch + (size_t)(row0 + row) * 128 + kh * 8);
        *(u16x8*)(r2 + 4096 + lws) = *(const u16x8*)(bcl + (size_t)(row0 + row) * 128 + kh * 8);
    }
    __syncthreads();
    // G = C @ B^T
    f32x4 accG[2][2];
    accG[0][0] = z4; accG[0][1] = z4; accG[1][0] = z4; accG[1][1] = z4;
    gemm3(r1, r2, ar0, wr0, lq, accG);
    __syncthreads();
    // mask -> P pairs into r1 ; stage X into r2
    const float Dph = Dp[h];
    #pragma unroll
    for (int fr = 0; fr < 2; fr++)
        #pragma unroll
        for (int fc = 0; fc < 2; fc++)
            #pragma unroll
            for (int r = 0; r < 4; r++) {
                int t = wm * 32 + fr * 16 + lq * 4 + r;
                int s = wn * 32 + fc * 16 + l15;
                float v = 0.f;
                if (s <= t) v = accG[fr][fc][r] * expf(la_sh[t] - la_sh[s]) * dt_sh[s];
                if (s == t) v += Dph;
                u16 hh = f2bf(v), ll = f2bf(v - bf2f(hh));
                int addr = (s >> 3) * 512 + ((t & 0x38) | ((t ^ (s >> 3)) & 7)) * 8 + (s & 7);
                r1[addr] = hh;
                r1[4096 + addr] = ll;
            }
    #pragma unroll
    for (int cc = 0; cc < 2; cc++) {
        int row = rr + cc * 32;
        int lws = kh * 512 + ((row & 0x38) | ((row ^ kh) & 7)) * 8;
        *(u16x8*)(r2 + lws)        = *(const u16x8*)(xTh + tile * 4096 + row * 64 + kh * 8);
        *(u16x8*)(r2 + 4096 + lws) = *(const u16x8*)(xTl + tile * 4096 + row * 64 + kh * 8);
    }
    __syncthreads();
    // Y1 = P @ X^T
    f32x4 acc1[2][2];
    acc1[0][0] = z4; acc1[0][1] = z4; acc1[1][0] = z4; acc1[1][1] = z4;
    gemm3(r1, r2, ar0, wr0, lq, acc1);
    // epilogue
    #pragma unroll
    for (int fr = 0; fr < 2; fr++)
        #pragma unroll
        for (int fc = 0; fc < 2; fc++)
            #pragma unroll
            for (int r = 0; r < 4; r++) {
                int t = wm * 32 + fr * 16 + lq * 4 + r;
                int p = wn * 32 + fc * 16 + l15;
                float Et = expf(la_sh[t]);
                y[(size_t)(row0 + t) * D_INNER + h * 64 + p] =
                    acc1[fr][fc][r] + Et * acc2[fr][fc][r];
            }
}

// gate with silu(z) + RMSNorm, then in-place per-row bf16 pair split
__global__ __launch_bounds__(256)
void gate_rmsnorm_pair_kernel(float* __restrict__ y, const float* __restrict__ z,
                              const float* __restrict__ norm_w)
{
    const int row = blockIdx.x;
    const float* zr = z + (size_t)row * D_INNER;
    float* yr = y + (size_t)row * D_INNER;
    const int tid = threadIdx.x;
    float g[6];
    float ss = 0.f;
    #pragma unroll
    for (int i = 0; i < 6; i++) {
        int e = tid + i * 256;
        float zv = zr[e];
        float gv = yr[e] * (zv / (1.f + expf(-zv)));
        g[i] = gv;
        ss = fmaf(gv, gv, ss);
    }
    #pragma unroll
    for (int o = 32; o > 0; o >>= 1) ss += __shfl_xor(ss, o);
    __shared__ float red[4];
    if ((tid & 63) == 0) red[tid >> 6] = ss;
    __syncthreads();
    float tot = red[0] + red[1] + red[2] + red[3];
    float scale = rsqrtf(tot * (1.f / D_INNER) + 1e-5f);
    u16* out = (u16*)yr;
    #pragma unroll
    for (int i = 0; i < 6; i++) {
        int e = tid + i * 256;
        float gv = g[i] * scale * norm_w[e];
        u16 h = f2bf(gv);
        out[e] = h;
        out[D_INNER + e] = f2bf(gv - bf2f(h));
    }
}

__global__ __launch_bounds__(256)
void layernorm_kernel(const float* __restrict__ r, const float* __restrict__ gam,
                      const float* __restrict__ bet, float* __restrict__ out)
{
    const int row = blockIdx.x;
    const float* rr = r + (size_t)row * D_MODEL;
    const int tid = threadIdx.x;
    float v[3];
    float s = 0.f, s2 = 0.f;
    #pragma unroll
    for (int i = 0; i < 3; i++) {
        v[i] = rr[tid + i * 256];
        s += v[i];
        s2 = fmaf(v[i], v[i], s2);
    }
    #pragma unroll
    for (int o = 32; o > 0; o >>= 1) { s += __shfl_xor(s, o); s2 += __shfl_xor(s2, o); }
    __shared__ float rs[4], rs2[4];
    if ((tid & 63) == 0) { rs[tid >> 6] = s; rs2[tid >> 6] = s2; }
    __syncthreads();
    float S  = rs[0] + rs[1] + rs[2] + rs[3];
    float S2 = rs2[0] + rs2[1] + rs2[2] + rs2[3];
    float mu  = S * (1.f / D_MODEL);
    float var = S2 * (1.f / D_MODEL) - mu * mu;
    float inv = rsqrtf(var + 1e-5f);
    #pragma unroll
    for (int i = 0; i < 3; i++) {
        int e = tid + i * 256;
        out[(size_t)row * D_MODEL + e] = (v[i] - mu) * inv * gam[e] + bet[e];
    }
}

extern "C" void kernel_launch(void* const* d_in, const int* in_sizes, int n_in,
                              void* d_out, int out_size, void* d_ws, size_t ws_size,
                              hipStream_t stream)
{
    const float* x        = (const float*)d_in[0];
    const int*   lengths  = (const int*)d_in[1];
    const float* in_w[2]    = {(const float*)d_in[2],  (const float*)d_in[10]};
    const float* conv_w[2]  = {(const float*)d_in[3],  (const float*)d_in[11]};
    const float* conv_b[2]  = {(const float*)d_in[4],  (const float*)d_in[12]};
    const float* dt_bias[2] = {(const float*)d_in[5],  (const float*)d_in[13]};
    const float* A_log[2]   = {(const float*)d_in[6],  (const float*)d_in[14]};
    const float* Dp[2]      = {(const float*)d_in[7],  (const float*)d_in[15]};
    const float* norm_w[2]  = {(const float*)d_in[8],  (const float*)d_in[16]};
    const float* out_w[2]   = {(const float*)d_in[9],  (const float*)d_in[17]};
    const float* op_w = (const float*)d_in[18];
    const float* op_b = (const float*)d_in[19];
    const float* ln_g = (const float*)d_in[20];
    const float* ln_b = (const float*)d_in[21];
    float* outp = (float*)d_out;

    // ---- workspace layout (262.4 MB, identical total footprint) ----
    float* z    = (float*)d_ws;                               // R0: 8192*1536
    float* xbcr = z + (size_t)NROWS * D_INNER;                // R1: 8192*1664 (-> hloc)
    float* la   = xbcr + (size_t)NROWS * CONV_DIM;            // R2a: 8192*24 (dtr -> la)
    float* dtb  = la  + (size_t)NROWS * NHEADS;               // R2b
    float* dtA  = dtb + (size_t)NROWS * NHEADS;               // R2c
    u16*  xTh   = (u16*)(dtA + (size_t)NROWS * NHEADS);       // R3: 8192*1536 u16
    u16*  xTl   = xTh + (size_t)NROWS * D_INNER;
    u16*  bch   = xTl + (size_t)NROWS * D_INNER;              //     8192*128 u16
    u16*  bcl   = bch + (size_t)NROWS * 128;
    float* ybuf = (float*)(bcl + (size_t)NROWS * 128);        // R4: 8192*1536
    u16*  comb_p = (u16*)(ybuf + (size_t)NROWS * D_INNER);    // R5: 8192*3072 u16

    float* hloc  = xbcr;          // after conv, xbcr dead -> chunk states
    float* xconv = ybuf;          // conv x-part f32, dead after transpose
    float* rbuf  = z;             // final pre-LN residual

    // conversion staging in R4 (dead outside in_proj) and R3 (dead after chunk_y)
    u16* xq_h = (u16*)ybuf;
    u16* xq_l = xq_h + (size_t)NROWS * D_MODEL;
    u16* iw_h = xq_l + (size_t)NROWS * D_MODEL;
    u16* iw_l = iw_h + (size_t)D_IN_PROJ * D_MODEL;
    u16* ow_h = xTh;
    u16* ow_l = ow_h + (size_t)D_MODEL * D_INNER;
    u16* op_h = xTh;
    u16* op_l = op_h + (size_t)D_MODEL * D_INNER;
    u16* yg_p = (u16*)ybuf;

    size_t need = ((size_t)NROWS * (D_INNER + CONV_DIM + 3*NHEADS + CONV_DIM +
                                    D_INNER + D_INNER)) * sizeof(float);
    if (ws_size < need) return;

    for (int dir = 0; dir < 2; dir++) {
        // 0. convert x and in_w to bf16 hi/lo (R4)
        convert_pair_kernel<<<(NROWS*D_MODEL/4 + 255)/256, 256, 0, stream>>>(
            x, xq_h, xq_l, NROWS*D_MODEL/4);
        convert_pair_kernel<<<(D_IN_PROJ*D_MODEL/4 + 255)/256, 256, 0, stream>>>(
            in_w[dir], iw_h, iw_l, D_IN_PROJ*D_MODEL/4);
        // 1. in_proj (split outputs): [z | xbcr | dtr=la]
        mfma_gemm<<<dim3(26, 64), 256, 0, stream>>>(
            xq_h, xq_l, D_MODEL, iw_h, iw_l, D_MODEL, D_IN_PROJ, D_MODEL,
            lengths, dir, 0, 1,
            nullptr, 0, z, xbcr, la, nullptr, 0, nullptr, nullptr);
        // 2. conv + silu: x-part f32 -> xconv (R4), B/C -> pairs (R3)
        conv_silu_split_kernel<<<dim3(7, NROWS), 256, 0, stream>>>(
            xbcr, conv_w[dir], conv_b[dir], xconv, bch, bcl);
        // 3. dt / dtA, then per-chunk cumsum -> la
        dt_kernel<<<(NROWS*NHEADS + 255)/256, 256, 0, stream>>>(
            la, dt_bias[dir], A_log[dir], dtb, dtA);
        cumsum_kernel<<<dim3(BATCH*NHEADS, NCHUNK), 64, 0, stream>>>(dtA, la);
        // 4. transpose x into per-chunk bf16-pair tiles
        transpose_pair_kernel<<<dim3(NHEADS, BATCH*NCHUNK), 256, 0, stream>>>(
            xconv, xTh, xTl);
        // 5. chunked SSD scan: states -> combine -> y
        chunk_state_kernel<<<dim3(BATCH*NHEADS, NCHUNK), 256, 0, stream>>>(
            xTh, xTl, bch, bcl, la, dtb, hloc);
        combine_kernel<<<BATCH*NHEADS, 256, 0, stream>>>(hloc, la);
        chunk_y_kernel<<<dim3(BATCH*NHEADS, NCHUNK), 256, 0, stream>>>(
            xTh, xTl, bch, bcl, hloc, la, dtb, Dp[dir], ybuf);
        // 6. gate + RMSNorm -> in-place bf16 pairs
        gate_rmsnorm_pair_kernel<<<NROWS, 256, 0, stream>>>(ybuf, z, norm_w[dir]);
        // 7. out_proj -> comb pairs (R3 dead -> out_w pairs)
        convert_pair_kernel<<<(D_MODEL*D_INNER/4 + 255)/256, 256, 0, stream>>>(
            out_w[dir], ow_h, ow_l, D_MODEL*D_INNER/4);
        mfma_gemm<<<dim3(6, 64), 256, 0, stream>>>(
            yg_p, yg_p + D_INNER, 3072, ow_h, ow_l, D_INNER, D_MODEL, D_INNER,
            lengths, 0, dir, 2,
            nullptr, 0, nullptr, nullptr, nullptr, comb_p, dir * D_MODEL,
            nullptr, nullptr);
    }

    // final: rbuf = comb @ op_w^T + op_b + x
    convert_pair_kernel<<<(D_MODEL*D_INNER/4 + 255)/256, 256, 0, stream>>>(
        op_w, op_h, op_l, D_MODEL*D_INNER/4);
    mfma_gemm<<<dim3(6, 64), 256, 0, stream>>>(
        comb_p, comb_p + 1536, 3072, op_h, op_l, 2*D_MODEL, D_MODEL, 2*D_MODEL,
        lengths, 0, 0, 0,
        rbuf, D_MODEL, nullptr, nullptr, nullptr, nullptr, 0, op_b, x);
    // layernorm -> out
    layernorm_kernel<<<NROWS, 256, 0, stream>>>(rbuf, ln_g, ln_b, outp);
}